// Round 11
// baseline (878.264 us; speedup 1.0000x reference)
//
#include <hip/hip_runtime.h>

#define D     200
#define H     4
#define DH    50
#define NE    38
#define NTY   4
#define NC    608      // edge combos = 38*4*4
#define NCT   612      // + 4 self combos
#define BG    256      // graphs
#define LG    1024     // edges per graph
#define EE    262144   // E
#define NN    51200    // N
#define EA    313344   // E + N
#define NB    200      // scan blocks = NN/256

#define NMATS  8       // Wk[:D], Wm[:D], Wq, Wo1, Wo2, Watt, Wk[D:], Wm[D:]
#define MROWS  128     // rows per GEMM block (4 row-groups x 32)
#define KS16   13      // K-steps of 16 (ceil(200/16))
#define SL32_SHORTS 8192   // one K-slice: 8 tiles * 2 halves * 512 shorts = 16384 B

typedef __attribute__((ext_vector_type(4)))  float f32x4;
typedef __attribute__((ext_vector_type(16))) float f32x16;
typedef __attribute__((ext_vector_type(8)))  short bf16x8;

__device__ __forceinline__ short bf_hi(float f) {
    unsigned u = __float_as_uint(f);
    unsigned r = u + 0x7fffu + ((u >> 16) & 1u);
    return (short)(r >> 16);
}
__device__ __forceinline__ float bf_f(short s) {
    return __uint_as_float(((unsigned)(unsigned short)s) << 16);
}

// ---------------- per-graph combo hist (LDS, no global atomics) + degrees + coef ----------------
__global__ __launch_bounds__(256) void k_hist(const int* __restrict__ ei, const int* __restrict__ et,
                                              const int* __restrict__ nt, int* outdeg, int* indeg,
                                              int* __restrict__ hcnt, float* coef) {
    __shared__ int loc[NC];
    int g = blockIdx.x, t = threadIdx.x;
    for (int i = t; i < NC; i += 256) loc[i] = 0;
    __syncthreads();
    #pragma unroll
    for (int j = 0; j < 4; j++) {
        int e = g * LG + j * 256 + t;
        int s = ei[e], d = ei[EE + e], tp = et[e];
        int c = tp * 16 + nt[s] * 4 + nt[d];
        atomicAdd(&loc[c], 1);
        atomicAdd(&outdeg[s], 1);
        atomicAdd(&indeg[d], 1);
        unsafeAtomicAdd(&coef[(size_t)d * NE + tp],  1.f);
        unsafeAtomicAdd(&coef[(size_t)s * NE + tp], -1.f);
    }
    __syncthreads();
    for (int i = t; i < NC; i += 256) hcnt[g * NC + i] = loc[i];
}

// hist[c] = sum_g hcnt[g*NC + c]  (coalesced column sums)
__global__ __launch_bounds__(256) void k_hist2(const int* __restrict__ hcnt, int* __restrict__ hist) {
    int c = blockIdx.x * 256 + threadIdx.x;
    if (c >= NC) return;
    int s = 0;
    for (int g = 0; g < BG; g++) s += hcnt[g * NC + c];
    hist[c] = s;
}

__global__ __launch_bounds__(256) void k_ntcnt(const int* __restrict__ nt, int* ntcnt) {
    __shared__ int loc[NTY];
    int t = threadIdx.x;
    if (t < NTY) loc[t] = 0;
    __syncthreads();
    int n = blockIdx.x * 256 + t;
    if (n < NN) atomicAdd(&loc[nt[n]], 1);
    __syncthreads();
    if (t < NTY) atomicAdd(&ntcnt[t], loc[t]);
}

__global__ void k_tcnt(const int* __restrict__ hist, int* tcnt) {
    int t = threadIdx.x;
    if (t < NE) { int s = 0; for (int i = 0; i < 16; i++) s += hist[t*16 + i]; tcnt[t] = s; }
}

// sums = coef^T (38 x NN) @ x (NN x 200), K-split GEMM.
__global__ __launch_bounds__(256) void k_xfsum3(const float* __restrict__ x, const float* __restrict__ coef,
                                                float* sums) {
    const int CH = NN / 256;   // 200 nodes per block
    int t = threadIdx.x;
    int n0 = blockIdx.x * CH;
    float acc[NE];
    #pragma unroll
    for (int m = 0; m < NE; m++) acc[m] = 0.f;
    if (t < D) {
        for (int k = 0; k < CH; k++) {
            int n = n0 + k;
            float xv = x[(size_t)n * D + t];
            const float* cf = coef + (size_t)n * NE;
            #pragma unroll
            for (int m = 0; m < NE; m++) acc[m] += cf[m] * xv;
        }
        #pragma unroll
        for (int m = 0; m < NE; m++)
            if (acc[m] != 0.f) unsafeAtomicAdd(&sums[m * D + t], acc[m]);
    }
}

// ---------------- CSR build: 3-phase parallel scan + scatter ----------------
__global__ __launch_bounds__(256) void k_scan_a(const int* __restrict__ a, const int* __restrict__ b,
                                                int* bsA, int* bsB) {
    __shared__ int redA[4], redB[4];
    int t = threadIdx.x, blk = blockIdx.x;
    int i = blk * 256 + t;
    int va = a[i], vb = b[i];
    for (int o = 1; o < 64; o <<= 1) { va += __shfl_xor(va, o); vb += __shfl_xor(vb, o); }
    int wave = t >> 6, lane = t & 63;
    if (lane == 0) { redA[wave] = va; redB[wave] = vb; }
    __syncthreads();
    if (t == 0) {
        bsA[blk] = redA[0] + redA[1] + redA[2] + redA[3];
        bsB[blk] = redB[0] + redB[1] + redB[2] + redB[3];
    }
}

__global__ __launch_bounds__(256) void k_scan_b(int* bsA, int* bsB, int* aoff, int* boff) {
    __shared__ int pa[256], pb[256];
    int t = threadIdx.x;
    int va = (t < NB) ? bsA[t] : 0;
    int vb = (t < NB) ? bsB[t] : 0;
    pa[t] = va; pb[t] = vb;
    __syncthreads();
    for (int off = 1; off < 256; off <<= 1) {
        int xa = (t >= off) ? pa[t - off] : 0;
        int xb = (t >= off) ? pb[t - off] : 0;
        __syncthreads();
        pa[t] += xa; pb[t] += xb;
        __syncthreads();
    }
    if (t < NB) { bsA[t] = pa[t] - va; bsB[t] = pb[t] - vb; }
    if (t == NB - 1) { aoff[NN] = pa[t]; boff[NN] = pb[t]; }
}

__global__ __launch_bounds__(256) void k_scan_c(const int* __restrict__ a, const int* __restrict__ b,
                                                const int* __restrict__ bsA, const int* __restrict__ bsB,
                                                int* aoff, int* boff, int* acur, int* bcur) {
    __shared__ int wsA[4], wsB[4];
    int t = threadIdx.x, blk = blockIdx.x;
    int i = blk * 256 + t;
    int va = a[i], vb = b[i];
    int wave = t >> 6, lane = t & 63;
    int sa = va, sb = vb;
    for (int o = 1; o < 64; o <<= 1) {
        int xa = __shfl_up(sa, o);
        int xb = __shfl_up(sb, o);
        if (lane >= o) { sa += xa; sb += xb; }
    }
    if (lane == 63) { wsA[wave] = sa; wsB[wave] = sb; }
    __syncthreads();
    int baseA = bsA[blk], baseB = bsB[blk];
    #pragma unroll
    for (int wv = 0; wv < 3; wv++) {
        if (wv < wave) { baseA += wsA[wv]; baseB += wsB[wv]; }
    }
    int ea = baseA + sa - va;   // exclusive
    int eb = baseB + sb - vb;
    aoff[i] = ea; acur[i] = ea;
    boff[i] = eb; bcur[i] = eb;
}

__global__ __launch_bounds__(256) void k_scatter(const int* __restrict__ ei, int* scur, int* dcur,
                                                 int* slist, int* dlist) {
    int e = blockIdx.x * 256 + threadIdx.x;
    if (e >= EE) return;
    int s = ei[e], d = ei[EE + e];
    slist[atomicAdd(&scur[s], 1)] = e;
    dlist[atomicAdd(&dcur[d], 1)] = e;
}

// ---------------- per-combo MLP pipeline ----------------
__global__ __launch_bounds__(256) void k_combos1(const float* __restrict__ We1, const float* __restrict__ be1,
                                                 const int* __restrict__ hist, const int* __restrict__ ntcnt,
                                                 float* __restrict__ h1, float* bn1) {
    int c = blockIdx.x, d = threadIdx.x;
    if (d >= D) return;
    float v, w;
    if (c < NC) {
        int etp = c >> 4, ts = (c >> 2) & 3, td = c & 3;
        v = We1[etp*D + d] + We1[(39+ts)*D + d] + We1[(43+td)*D + d] + be1[d];
        w = (float)hist[c];
    } else {
        int t = c - NC;
        v = We1[38*D + d] + We1[(39+t)*D + d] + We1[(43+t)*D + d] + be1[d];
        w = (float)ntcnt[t];
    }
    h1[c*D + d] = v;
    unsafeAtomicAdd(&bn1[d], w * v);
    unsafeAtomicAdd(&bn1[D + d], w * v * v);
}

__global__ __launch_bounds__(256) void k_combos2(const float* __restrict__ h1, const float* __restrict__ bn1,
                                                 const float* __restrict__ ge1, const float* __restrict__ bte1,
                                                 const float* __restrict__ We2, const float* __restrict__ be2,
                                                 float* __restrict__ embE, float* __restrict__ embS) {
    __shared__ float v[D];
    int c = blockIdx.x, t = threadIdx.x;
    if (t < D) {
        float cnt = (float)(EE + NN);
        float m = bn1[t] / cnt;
        float var = bn1[D + t] / cnt - m * m;
        float r = rsqrtf(var + 1e-5f);
        float u = (h1[c*D + t] - m) * r * ge1[t] + bte1[t];
        v[t] = fmaxf(u, 0.f);
    }
    __syncthreads();
    if (t < D) {
        float acc = be2[t];
        for (int k = 0; k < D; k++) acc += v[k] * We2[k*D + t];
        if (c < NC) embE[c*D + t] = acc; else embS[(c-NC)*D + t] = acc;
    }
}

__global__ __launch_bounds__(256) void k_combos3(const float* __restrict__ embE, const float* __restrict__ sumsxf,
                                                 const int* __restrict__ tcnt, const float* __restrict__ Wa1,
                                                 const float* __restrict__ ba1, const int* __restrict__ hist,
                                                 float* __restrict__ h2, float* bn2) {
    __shared__ float a[2*D];
    int c = blockIdx.x, t = threadIdx.x;
    int etp = c >> 4;
    if (t < D) {
        a[t] = embE[c*D + t];
        float cn = fmaxf((float)tcnt[etp], 1.f);
        a[D + t] = sumsxf[etp*D + t] / cn;
    }
    __syncthreads();
    if (t < D) {
        float acc = ba1[t];
        for (int k = 0; k < 2*D; k++) acc += a[k] * Wa1[k*D + t];
        h2[c*D + t] = acc;
        float w = (float)hist[c];
        unsafeAtomicAdd(&bn2[t], w * acc);
        unsafeAtomicAdd(&bn2[D + t], w * acc * acc);
    }
}

// also writes RcT (200 x 608) for the coalesced attention score pass
__global__ __launch_bounds__(256) void k_combos4(const float* __restrict__ h2, const float* __restrict__ bn2,
                                                 const float* __restrict__ ga1, const float* __restrict__ bta1,
                                                 const float* __restrict__ Wa2, const float* __restrict__ ba2,
                                                 float* __restrict__ Rc, float* __restrict__ RcT) {
    __shared__ float v[D];
    int c = blockIdx.x, t = threadIdx.x;
    if (t < D) {
        float inv = 1.f / (float)EE;
        float m = bn2[t] * inv;
        float var = bn2[D + t] * inv - m * m;
        float r = rsqrtf(var + 1e-5f);
        float u = (h2[c*D + t] - m) * r * ga1[t] + bta1[t];
        v[t] = fmaxf(u, 0.f);
    }
    __syncthreads();
    if (t < D) {
        float acc = ba2[t];
        for (int k = 0; k < D; k++) acc += v[k] * Wa2[k*D + t];
        Rc[c*D + t] = acc;
        RcT[(size_t)t * NC + c] = acc;
    }
}

// ---------------- per-graph attention: qs precomputed by MFMA, 8-wave latency-hiding ----------------
__global__ __launch_bounds__(512) void k_attn(const float* __restrict__ qs,
                                              const float* __restrict__ Rc, const float* __restrict__ RcT,
                                              const int* __restrict__ hcnt, float* __restrict__ upd) {
    __shared__ float q[D];
    __shared__ float w[NC];
    __shared__ float red[16];
    __shared__ float part[8][D];
    int b = blockIdx.x, t = threadIdx.x;
    int wave = t >> 6, lane = t & 63;
    if (t < D) q[t] = qs[b*D + t];   // already scaled by 1/sqrt(200)
    __syncthreads();
    {
        float s0a = 0.f, s0b = 0.f, s0c = 0.f, s0d = 0.f;
        float s1a = 0.f, s1b = 0.f, s1c = 0.f, s1d = 0.f;
        for (int k = 0; k < D; k += 4) {
            float q0 = q[k], q1 = q[k+1], q2 = q[k+2], q3 = q[k+3];
            const float* r = RcT + (size_t)k * NC;
            s0a += q0 * r[t];
            s0b += q1 * r[NC + t];
            s0c += q2 * r[2*NC + t];
            s0d += q3 * r[3*NC + t];
            if (t < NC - 512) {
                s1a += q0 * r[t + 512];
                s1b += q1 * r[NC + t + 512];
                s1c += q2 * r[2*NC + t + 512];
                s1d += q3 * r[3*NC + t + 512];
            }
        }
        w[t] = (s0a + s0b) + (s0c + s0d);
        if (t < NC - 512) w[t + 512] = (s1a + s1b) + (s1c + s1d);
    }
    __syncthreads();
    float mx = -1e30f;
    for (int c = t; c < NC; c += 512) mx = fmaxf(mx, w[c]);
    for (int o = 32; o; o >>= 1) mx = fmaxf(mx, __shfl_xor(mx, o));
    if (lane == 0) red[wave] = mx;
    __syncthreads();
    mx = red[0];
    #pragma unroll
    for (int i = 1; i < 8; i++) mx = fmaxf(mx, red[i]);
    float sm = 0.f;
    for (int c = t; c < NC; c += 512) {
        float wv = (float)hcnt[b * NC + c] * __expf(w[c] - mx);
        w[c] = wv;
        sm += wv;
    }
    for (int o = 32; o; o >>= 1) sm += __shfl_xor(sm, o);
    if (lane == 0) red[8 + wave] = sm;
    __syncthreads();
    float tot = red[8];
    #pragma unroll
    for (int i = 1; i < 8; i++) tot += red[8 + i];
    float inv = 1.f / tot;
    float a4[4] = {0.f, 0.f, 0.f, 0.f};
    for (int c = wave * (NC/8); c < (wave + 1) * (NC/8); c++) {
        float wv = w[c];
        const float* r = Rc + c * D;
        #pragma unroll
        for (int j = 0; j < 4; j++) { int dd = lane + 64*j; if (dd < D) a4[j] += wv * r[dd]; }
    }
    #pragma unroll
    for (int j = 0; j < 4; j++) { int dd = lane + 64*j; if (dd < D) part[wave][dd] = a4[j]; }
    __syncthreads();
    if (t < D) {
        float s = part[0][t];
        #pragma unroll
        for (int i = 1; i < 8; i++) s += part[i][t];
        upd[b*D + t] = s * inv;
    }
}

// ---------------- weight packing: 32x32x16 fragment order, ks-major slices, bf16 hi/lo ----------------
// blk = mat*13 + ks. Slice = 8 col-tiles (cols padded 200->256) x {hi,lo} x 512 shorts = 16384 B.
// B-operand layout for mfma_f32_32x32x16_bf16: col n = lane&31, k = (lane>>5)*8 + j (8 contiguous k).
// mats: 0=Wk[:D] 1=Wm[:D] 2=Wq 3=Wo1 4=Wo2 5=Watt 6=Wk[D:] 7=Wm[D:]
__global__ __launch_bounds__(256) void k_packW(const float* __restrict__ Wk, const float* __restrict__ Wm,
                                               const float* __restrict__ Wq, const float* __restrict__ Wo1,
                                               const float* __restrict__ Wo2, const float* __restrict__ Watt,
                                               short* __restrict__ Bpk) {
    int blk = blockIdx.x;                // mat*13 + ks
    int mat = blk / KS16, ks = blk - mat * KS16;
    const float* W = (mat == 0) ? Wk : (mat == 1) ? Wm : (mat == 2) ? Wq : (mat == 3) ? Wo1 :
                     (mat == 4) ? Wo2 : (mat == 5) ? Watt : (mat == 6) ? (Wk + D*D) : (Wm + D*D);
    int t = threadIdx.x;
    for (int idx = t; idx < SL32_SHORTS; idx += 256) {
        int frag = idx >> 9;             // tile*2 + half
        int within = idx & 511;
        int tile = frag >> 1, half = frag & 1;
        int lane = within >> 3, j = within & 7;
        int n = tile * 32 + (lane & 31);
        int k = ks * 16 + ((lane >> 5) << 3) + j;
        float v = (k < D && n < D) ? W[k * D + n] : 0.f;
        short h = bf_hi(v);
        short out = half ? bf_hi(v - bf_f(h)) : h;
        Bpk[(size_t)blk * SL32_SHORTS + idx] = out;
    }
}

// ---------------- MFMA GEMM core: 32x32x16, 8 waves = 4 row-groups x 2 col-groups ----------------
// Each wave owns 32 rows x 4 col-tiles of 32. One bh/bl pair (2KB) feeds 3 MFMAs of 32K FLOP
// -> 0.021 LDS-B/FLOP (2x round-7's 16x16 core) with acc = 4 x f32x16 = 64 VGPR (fits 128 bucket).
__device__ __forceinline__ void stage_load32(const short* __restrict__ g, int w, int lane, f32x4 rg[2]) {
    rg[0] = *(const f32x4*)((const char*)g + w * 1024 + lane * 16);
    rg[1] = *(const f32x4*)((const char*)g + (w + 8) * 1024 + lane * 16);
}
__device__ __forceinline__ void stage_write32(short* l, int w, int lane, const f32x4 rg[2]) {
    *(f32x4*)((char*)l + w * 1024 + lane * 16) = rg[0];
    *(f32x4*)((char*)l + (w + 8) * 1024 + lane * 16) = rg[1];
}

// A-operand: row m = lane&31, k = ks*16 + (lane>>5)*8 + j  (8 contiguous floats, 32B-aligned)
__device__ __forceinline__ void load_afrag32(const float* __restrict__ A, int row, int khalf, int ks,
                                             int preop, const float* __restrict__ bnacc, float invCnt,
                                             const float* __restrict__ g, const float* __restrict__ bb,
                                             bf16x8& ah, bf16x8& al) {
    int k0 = ks * 16 + khalf * 8;
    float v[8];
    if (k0 < D) {   // k0 multiple of 8; k0 <= 192 => k0+8 <= 200, always in-row
        const float* src = A + (size_t)row * D + k0;
        float4 p0 = *(const float4*)src;
        float4 p1 = *(const float4*)(src + 4);
        v[0]=p0.x; v[1]=p0.y; v[2]=p0.z; v[3]=p0.w;
        v[4]=p1.x; v[5]=p1.y; v[6]=p1.z; v[7]=p1.w;
        if (preop) {
            float4 m0 = *(const float4*)(bnacc + k0);
            float4 m1 = *(const float4*)(bnacc + k0 + 4);
            float4 q0 = *(const float4*)(bnacc + D + k0);
            float4 q1 = *(const float4*)(bnacc + D + k0 + 4);
            float4 g0 = *(const float4*)(g + k0);
            float4 g1 = *(const float4*)(g + k0 + 4);
            float4 b0 = *(const float4*)(bb + k0);
            float4 b1 = *(const float4*)(bb + k0 + 4);
            float mm[8] = {m0.x,m0.y,m0.z,m0.w,m1.x,m1.y,m1.z,m1.w};
            float qq[8] = {q0.x,q0.y,q0.z,q0.w,q1.x,q1.y,q1.z,q1.w};
            float gg[8] = {g0.x,g0.y,g0.z,g0.w,g1.x,g1.y,g1.z,g1.w};
            float bv[8] = {b0.x,b0.y,b0.z,b0.w,b1.x,b1.y,b1.z,b1.w};
            #pragma unroll
            for (int j = 0; j < 8; j++) {
                float mj = mm[j] * invCnt;
                float var = qq[j] * invCnt - mj * mj;
                float rs = rsqrtf(var + 1e-5f);
                float s = rs * gg[j];
                v[j] = fmaxf(v[j] * s + (bv[j] - mj * s), 0.f);
            }
        }
    } else {
        #pragma unroll
        for (int j = 0; j < 8; j++) v[j] = 0.f;
    }
    #pragma unroll
    for (int j = 0; j < 8; j++) {
        short h = bf_hi(v[j]);
        ah[j] = h;
        al[j] = bf_hi(v[j] - bf_f(h));
    }
}

// C/D layout (HW-verified): col = lane&31, row = (r&3) + 8*(r>>2) + 4*(lane>>5), r in [0,16)
__device__ __forceinline__ void store_C32(const f32x16& a, float* __restrict__ C, int n0, int rowg,
                                          int tg, int lane, const float* __restrict__ bias, float postscale) {
    int col = tg * 32 + (lane & 31);
    if (col < D) {
        float bj = bias ? bias[col] : 0.f;
        int rbase = n0 + rowg * 32 + 4 * (lane >> 5);
        #pragma unroll
        for (int r = 0; r < 16; r++) {
            int row = rbase + (r & 3) + 8 * (r >> 2);
            C[(size_t)row * D + col] = (a[r] + bj) * postscale;
        }
    }
}

// one K16-step: prefetch slice u+1, load A pair, 3 MFMAs per owned tile, write prefetched, barrier.
#define MMF32_KS(MATV, KS, NUTOT, BASE)                                           \
    {                                                                             \
        int u_ = (MATV) * KS16 + (KS);                                            \
        int cur_ = u_ & 1;                                                        \
        if (u_ + 1 < (NUTOT))                                                     \
            stage_load32((BASE) + (size_t)(u_ + 1) * SL32_SHORTS, w, lane, rg);   \
        bf16x8 ah_, al_;                                                          \
        load_afrag32(A, row, khalf, KS, preop_, bnacc_, invCnt_, g_, bb_, ah_, al_); \
        const bf16x8* B8_ = (const bf16x8*)(Bls + cur_ * SL32_SHORTS);            \
        { bf16x8 bh = B8_[((tb+0)*2+0)*64 + lane], bl = B8_[((tb+0)*2+1)*64 + lane]; \
          acc0 = __builtin_amdgcn_mfma_f32_32x32x16_bf16(al_, bh, acc0, 0, 0, 0); \
          acc0 = __builtin_amdgcn_mfma_f32_32x32x16_bf16(ah_, bl, acc0, 0, 0, 0); \
          acc0 = __builtin_amdgcn_mfma_f32_32x32x16_bf16(ah_, bh, acc0, 0, 0, 0); } \
        { bf16x8 bh = B8_[((tb+1)*2+0)*64 + lane], bl = B8_[((tb+1)*2+1)*64 + lane]; \
          acc1 = __builtin_amdgcn_mfma_f32_32x32x16_bf16(al_, bh, acc1, 0, 0, 0); \
          acc1 = __builtin_amdgcn_mfma_f32_32x32x16_bf16(ah_, bl, acc1, 0, 0, 0); \
          acc1 = __builtin_amdgcn_mfma_f32_32x32x16_bf16(ah_, bh, acc1, 0, 0, 0); } \
        { bf16x8 bh = B8_[((tb+2)*2+0)*64 + lane], bl = B8_[((tb+2)*2+1)*64 + lane]; \
          acc2 = __builtin_amdgcn_mfma_f32_32x32x16_bf16(al_, bh, acc2, 0, 0, 0); \
          acc2 = __builtin_amdgcn_mfma_f32_32x32x16_bf16(ah_, bl, acc2, 0, 0, 0); \
          acc2 = __builtin_amdgcn_mfma_f32_32x32x16_bf16(ah_, bh, acc2, 0, 0, 0); } \
        { bf16x8 bh = B8_[((tb+3)*2+0)*64 + lane], bl = B8_[((tb+3)*2+1)*64 + lane]; \
          acc3 = __builtin_amdgcn_mfma_f32_32x32x16_bf16(al_, bh, acc3, 0, 0, 0); \
          acc3 = __builtin_amdgcn_mfma_f32_32x32x16_bf16(ah_, bl, acc3, 0, 0, 0); \
          acc3 = __builtin_amdgcn_mfma_f32_32x32x16_bf16(ah_, bh, acc3, 0, 0, 0); } \
        if (u_ + 1 < (NUTOT)) {                                                   \
            stage_write32(Bls + (cur_ ^ 1) * SL32_SHORTS, w, lane, rg);           \
            __syncthreads();                                                      \
        }                                                                         \
    }

#define ZERO_ACCS() { _Pragma("unroll") for (int r_ = 0; r_ < 16; r_++) { acc0[r_]=0.f; acc1[r_]=0.f; acc2[r_]=0.f; acc3[r_]=0.f; } }

// ---------------- fused x @ {Wk[:D], Wm[:D], Wq} ----------------
__global__ __launch_bounds__(512, 2) void k_mmf3(const float* __restrict__ A, const short* __restrict__ Bpk,
                                                 const float* __restrict__ bq,
                                                 float* __restrict__ XK, float* __restrict__ XM, float* __restrict__ XQ) {
    __shared__ __align__(16) short Bls[2 * SL32_SHORTS];   // 32768 B
    int t = threadIdx.x, w = t >> 6, lane = t & 63;
    int n0 = blockIdx.x * MROWS;
    int rowg = w >> 1, colg = w & 1;
    int tb = colg * 4;
    int row = n0 + rowg * 32 + (lane & 31);
    int khalf = lane >> 5;
    int preop_ = 0; const float* bnacc_ = nullptr; float invCnt_ = 0.f;
    const float* g_ = nullptr; const float* bb_ = nullptr;
    f32x4 rg[2];
    stage_load32(Bpk, w, lane, rg);
    stage_write32(Bls, w, lane, rg);
    __syncthreads();
    f32x16 acc0, acc1, acc2, acc3;
    for (int mat = 0; mat < 3; ++mat) {
        ZERO_ACCS()
        MMF32_KS(mat,  0, 3*KS16, Bpk)
        MMF32_KS(mat,  1, 3*KS16, Bpk)
        MMF32_KS(mat,  2, 3*KS16, Bpk)
        MMF32_KS(mat,  3, 3*KS16, Bpk)
        MMF32_KS(mat,  4, 3*KS16, Bpk)
        MMF32_KS(mat,  5, 3*KS16, Bpk)
        MMF32_KS(mat,  6, 3*KS16, Bpk)
        MMF32_KS(mat,  7, 3*KS16, Bpk)
        MMF32_KS(mat,  8, 3*KS16, Bpk)
        MMF32_KS(mat,  9, 3*KS16, Bpk)
        MMF32_KS(mat, 10, 3*KS16, Bpk)
        MMF32_KS(mat, 11, 3*KS16, Bpk)
        MMF32_KS(mat, 12, 3*KS16, Bpk)
        float* C = (mat == 0) ? XK : (mat == 1) ? XM : XQ;
        const float* bias = (mat == 2) ? bq : nullptr;
        float ps = (mat == 2) ? 0.14142135623730950488f : 1.f;
        store_C32(acc0, C, n0, rowg, tb + 0, lane, bias, ps);
        store_C32(acc1, C, n0, rowg, tb + 1, lane, bias, ps);
        store_C32(acc2, C, n0, rowg, tb + 2, lane, bias, ps);
        store_C32(acc3, C, n0, rowg, tb + 3, lane, bias, ps);
    }
}

// ---------------- generic MFMA matmul (one B), optional BN+relu preop ----------------
__global__ __launch_bounds__(512, 2) void k_mmf(const float* __restrict__ A, const short* __restrict__ Bmat,
                                                const float* __restrict__ bias, float* __restrict__ C,
                                                int preop, const float* __restrict__ bnacc, float invCnt,
                                                const float* __restrict__ g, const float* __restrict__ bb,
                                                float postscale) {
    __shared__ __align__(16) short Bls[2 * SL32_SHORTS];
    int t = threadIdx.x, w = t >> 6, lane = t & 63;
    int n0 = blockIdx.x * MROWS;
    int rowg = w >> 1, colg = w & 1;
    int tb = colg * 4;
    int row = n0 + rowg * 32 + (lane & 31);
    int khalf = lane >> 5;
    int preop_ = preop; const float* bnacc_ = bnacc; float invCnt_ = invCnt;
    const float* g_ = g; const float* bb_ = bb;
    f32x4 rg[2];
    stage_load32(Bmat, w, lane, rg);
    stage_write32(Bls, w, lane, rg);
    __syncthreads();
    f32x16 acc0, acc1, acc2, acc3;
    ZERO_ACCS()
    MMF32_KS(0,  0, KS16, Bmat)
    MMF32_KS(0,  1, KS16, Bmat)
    MMF32_KS(0,  2, KS16, Bmat)
    MMF32_KS(0,  3, KS16, Bmat)
    MMF32_KS(0,  4, KS16, Bmat)
    MMF32_KS(0,  5, KS16, Bmat)
    MMF32_KS(0,  6, KS16, Bmat)
    MMF32_KS(0,  7, KS16, Bmat)
    MMF32_KS(0,  8, KS16, Bmat)
    MMF32_KS(0,  9, KS16, Bmat)
    MMF32_KS(0, 10, KS16, Bmat)
    MMF32_KS(0, 11, KS16, Bmat)
    MMF32_KS(0, 12, KS16, Bmat)
    store_C32(acc0, C, n0, rowg, tb + 0, lane, bias, postscale);
    store_C32(acc1, C, n0, rowg, tb + 1, lane, bias, postscale);
    store_C32(acc2, C, n0, rowg, tb + 2, lane, bias, postscale);
    store_C32(acc3, C, n0, rowg, tb + 3, lane, bias, postscale);
}

// 7-shuffle reduce-scatter: input 4 head partials/lane; output: lane group g (lane>>4) holds head-g total
__device__ __forceinline__ float head_reduce(float h0, float h1, float h2, float h3, int lane) {
    float ax = (lane < 32) ? h2 : h0;
    float ay = (lane < 32) ? h3 : h1;
    float u0 = ((lane < 32) ? h0 : h2) + __shfl_xor(ax, 32);
    float u1 = ((lane < 32) ? h1 : h3) + __shfl_xor(ay, 32);
    float bx = ((lane & 16) == 0) ? u1 : u0;
    float v  = (((lane & 16) == 0) ? u0 : u1) + __shfl_xor(bx, 16);
    v += __shfl_xor(v, 8);
    v += __shfl_xor(v, 4);
    v += __shfl_xor(v, 2);
    v += __shfl_xor(v, 1);
    return v;
}

// ---------------- edge softmax, src-CSR, wave per node; d = head*50 + lane ----------------
__global__ __launch_bounds__(256) void k_soft(const int* __restrict__ ei, const int* __restrict__ nt,
                                              const int* __restrict__ soff, const int* __restrict__ slist,
                                              const int* __restrict__ outdeg,
                                              const float* __restrict__ XQ, const float* __restrict__ XK,
                                              const float* __restrict__ GK, const float* __restrict__ SK,
                                              float* __restrict__ sc, float* __restrict__ scale) {
    int wave = threadIdx.x >> 6, lane = threadIdx.x & 63;
    int n = blockIdx.x * 4 + wave;
    if (n >= NN) return;
    bool act = lane < DH;
    int grp = lane >> 4;
    float qv0 = 0.f, qv1 = 0.f, qv2 = 0.f, qv3 = 0.f;
    if (act) {
        const float* q = XQ + (size_t)n * D + lane;
        qv0 = q[0]; qv1 = q[DH]; qv2 = q[2*DH]; qv3 = q[3*DH];
    }
    float den = 0.f;
    {   // self edge
        int tn = nt[n];
        float h0 = 0.f, h1 = 0.f, h2 = 0.f, h3 = 0.f;
        if (act) {
            const float* xk = XK + (size_t)n * D + lane;
            const float* sk = SK + (size_t)tn * D + lane;
            h0 = qv0 * (xk[0]    + sk[0]);
            h1 = qv1 * (xk[DH]   + sk[DH]);
            h2 = qv2 * (xk[2*DH] + sk[2*DH]);
            h3 = qv3 * (xk[3*DH] + sk[3*DH]);
        }
        float v = head_reduce(h0, h1, h2, h3, lane);
        float e = __expf(v);
        den += e;
        if ((lane & 15) == 0) sc[(size_t)(EE + n) * 4 + grp] = e;
    }
    int beg = soff[n], end = soff[n + 1];
    for (int i = beg; i < end; i++) {
        int e_ = slist[i];
        int tail = ei[EE + e_];
        int g = e_ >> 10;
        float h0 = 0.f, h1 = 0.f, h2 = 0.f, h3 = 0.f;
        if (act) {
            const float* xk = XK + (size_t)tail * D + lane;
            const float* gk = GK + (size_t)g * D + lane;
            h0 = qv0 * (xk[0]    + gk[0]);
            h1 = qv1 * (xk[DH]   + gk[DH]);
            h2 = qv2 * (xk[2*DH] + gk[2*DH]);
            h3 = qv3 * (xk[3*DH] + gk[3*DH]);
        }
        float v = head_reduce(h0, h1, h2, h3, lane);
        float e = __expf(v);
        den += e;
        if ((lane & 15) == 0) sc[(size_t)e_ * 4 + grp] = e;
    }
    float cnt = (float)(outdeg[n] + 1);
    if ((lane & 15) == 0) scale[(size_t)n * 4 + grp] = cnt / den;
}

// ---------------- aggregation, dst-CSR, wave per node; d = head*50 + lane ----------------
__global__ __launch_bounds__(256) void k_aggr(const int* __restrict__ ei, const int* __restrict__ nt,
                                              const int* __restrict__ doff, const int* __restrict__ dlist,
                                              const float* __restrict__ sc, const float* __restrict__ scale,
                                              const float* __restrict__ XM, const float* __restrict__ GM,
                                              const float* __restrict__ SM, float* __restrict__ aggr) {
    int wave = threadIdx.x >> 6, lane = threadIdx.x & 63;
    int n = blockIdx.x * 4 + wave;
    if (n >= NN) return;
    bool act = lane < DH;
    float acc0 = 0.f, acc1 = 0.f, acc2 = 0.f, acc3 = 0.f;
    {   // self edge
        int tn = nt[n];
        float4 ss = *(const float4*)&sc[(size_t)(EE + n) * 4];
        float4 sl = *(const float4*)&scale[(size_t)n * 4];
        if (act) {
            const float* xm = XM + (size_t)n * D + lane;
            const float* sm = SM + (size_t)tn * D + lane;
            acc0 += ss.x * sl.x * (xm[0]    + sm[0]);
            acc1 += ss.y * sl.y * (xm[DH]   + sm[DH]);
            acc2 += ss.z * sl.z * (xm[2*DH] + sm[2*DH]);
            acc3 += ss.w * sl.w * (xm[3*DH] + sm[3*DH]);
        }
    }
    int beg = doff[n], end = doff[n + 1];
    for (int i = beg; i < end; i++) {
        int e = dlist[i];
        int s = ei[e];
        int g = e >> 10;
        float4 ss = *(const float4*)&sc[(size_t)e * 4];
        float4 sl = *(const float4*)&scale[(size_t)s * 4];
        if (act) {
            const float* xm = XM + (size_t)s * D + lane;
            const float* gm = GM + (size_t)g * D + lane;
            acc0 += ss.x * sl.x * (xm[0]    + gm[0]);
            acc1 += ss.y * sl.y * (xm[DH]   + gm[DH]);
            acc2 += ss.z * sl.z * (xm[2*DH] + gm[2*DH]);
            acc3 += ss.w * sl.w * (xm[3*DH] + gm[3*DH]);
        }
    }
    if (act) {
        float* out = aggr + (size_t)n * D + lane;
        out[0]    = acc0;
        out[DH]   = acc1;
        out[2*DH] = acc2;
        out[3*DH] = acc3;
    }
}

// ---------------- column stats for final BN ----------------
__global__ __launch_bounds__(256) void k_colstats(const float* __restrict__ T1, float* bn3) {
    int t = threadIdx.x;
    if (t >= D) return;
    int r0 = blockIdx.x * 256;
    float s = 0.f, q = 0.f;
    for (int r = r0; r < r0 + 256; r++) {
        float v = T1[(size_t)r * D + t];
        s += v; q += v * v;
    }
    unsafeAtomicAdd(&bn3[t], s);
    unsafeAtomicAdd(&bn3[D + t], q);
}

extern "C" void kernel_launch(void* const* d_in, const int* in_sizes, int n_in,
                              void* d_out, int out_size, void* d_ws, size_t ws_size,
                              hipStream_t stream) {
    const float* x    = (const float*)d_in[0];
    const float* sent = (const float*)d_in[2];
    const float* We1  = (const float*)d_in[3];
    const float* be1  = (const float*)d_in[4];
    const float* ge1  = (const float*)d_in[5];
    const float* bte1 = (const float*)d_in[6];
    const float* We2  = (const float*)d_in[7];
    const float* be2  = (const float*)d_in[8];
    const float* Wa1  = (const float*)d_in[9];
    const float* ba1  = (const float*)d_in[10];
    const float* ga1  = (const float*)d_in[11];
    const float* bta1 = (const float*)d_in[12];
    const float* Wa2  = (const float*)d_in[13];
    const float* ba2  = (const float*)d_in[14];
    const float* Watt = (const float*)d_in[15];
    const float* Wk   = (const float*)d_in[16];
    const float* bk   = (const float*)d_in[17];
    const float* Wm   = (const float*)d_in[18];
    const float* bm   = (const float*)d_in[19];
    const float* Wq   = (const float*)d_in[20];
    const float* bq   = (const float*)d_in[21];
    const float* Wo1  = (const float*)d_in[22];
    const float* bo1  = (const float*)d_in[23];
    const float* go1  = (const float*)d_in[24];
    const float* bto1 = (const float*)d_in[25];
    const float* Wo2  = (const float*)d_in[26];
    const float* bo2  = (const float*)d_in[27];
    const int* ei = (const int*)d_in[28];
    const int* et = (const int*)d_in[29];
    const int* nt = (const int*)d_in[30];

    char* ws = (char*)d_ws;
    size_t off = 0;
    auto alloc = [&](size_t bytes) -> char* {
        char* p = ws + off;
        off = (off + bytes + 255) & ~(size_t)255;
        return p;
    };
    // ---- zeroed region ----
    int*   hist   = (int*)  alloc(NC * 4);
    int*   ntcnt  = (int*)  alloc(NTY * 4);
    float* bn1    = (float*)alloc(2 * D * 4);
    float* bn2    = (float*)alloc(2 * D * 4);
    float* bn3    = (float*)alloc(2 * D * 4);
    float* sumsxf = (float*)alloc(NE * D * 4);
    int*   outdeg = (int*)  alloc(NN * 4);
    int*   indeg  = (int*)  alloc(NN * 4);
    int*   hcnt   = (int*)  alloc((size_t)BG * NC * 4);   // per-graph combo histogram
    float* updS   = (float*)alloc((size_t)384 * D * 4);   // rows: 0..255 upd, 256..259 embS, 260..383 pad
    size_t zero_end = off;
    // ---- rest ----
    int* tcnt = (int*)alloc(NE * 4);
    int* soff_ = (int*)alloc((NN + 1) * 4);
    int* doff_ = (int*)alloc((NN + 1) * 4);
    int* scur = (int*)alloc(NN * 4);
    int* dcur = (int*)alloc(NN * 4);
    int* bsA  = (int*)alloc(NB * 4);
    int* bsB  = (int*)alloc(NB * 4);
    int* slist = (int*)alloc((size_t)EE * 4);
    int* dlist = (int*)alloc((size_t)EE * 4);
    short* Bpk  = (short*)alloc((size_t)NMATS * KS16 * SL32_SHORTS * 2);   // 8 mats, 32x32 frag order
    float* h1v   = (float*)alloc((size_t)NCT * D * 4);
    float* embE  = (float*)alloc((size_t)NC * D * 4);
    float* h2pre = (float*)alloc((size_t)NC * D * 4);
    float* Rc    = (float*)alloc((size_t)NC * D * 4);
    float* RcT   = (float*)alloc((size_t)D * NC * 4);
    float* qs    = (float*)alloc((size_t)BG * D * 4);
    float* GK    = (float*)alloc((size_t)384 * D * 4);    // rows 256..259 = SK
    float* GM    = (float*)alloc((size_t)384 * D * 4);    // rows 256..259 = SM
    float* sc    = (float*)alloc((size_t)EA * H * 4);
    float* XK    = (float*)alloc((size_t)NN * D * 4);
    float* XM    = (float*)alloc((size_t)NN * D * 4);
    float* XQ    = (float*)alloc((size_t)NN * D * 4);
    // aliases (liveness-checked):
    float* coef  = XK;            // dead before k_mmf3 writes XK
    float* scale = h1v;           // h1v dead before k_soft writes scale
    float* aggr  = XQ;            // XQ dead after k_soft
    float* T1    = XK;            // XK dead after k_soft
    float* embS  = updS + 256 * D;
    float* SK    = GK + 256 * D;
    float* SM    = GM + 256 * D;

    const size_t matstride = (size_t)KS16 * SL32_SHORTS;   // shorts per packed mat

    hipMemsetAsync(ws, 0, zero_end, stream);
    hipMemsetAsync(coef, 0, (size_t)NN * NE * 4, stream);

    k_packW  <<<NMATS * KS16, 256, 0, stream>>>(Wk, Wm, Wq, Wo1, Wo2, Watt, Bpk);
    k_hist   <<<BG, 256, 0, stream>>>(ei, et, nt, outdeg, indeg, hcnt, coef);
    k_hist2  <<<3, 256, 0, stream>>>(hcnt, hist);
    k_ntcnt  <<<NN / 256, 256, 0, stream>>>(nt, ntcnt);
    k_tcnt   <<<1, 64, 0, stream>>>(hist, tcnt);
    k_scan_a <<<NB, 256, 0, stream>>>(outdeg, indeg, bsA, bsB);
    k_scan_b <<<1, 256, 0, stream>>>(bsA, bsB, soff_, doff_);
    k_scan_c <<<NB, 256, 0, stream>>>(outdeg, indeg, bsA, bsB, soff_, doff_, scur, dcur);
    k_scatter<<<EE / 256, 256, 0, stream>>>(ei, scur, dcur, slist, dlist);
    k_xfsum3 <<<256, 256, 0, stream>>>(x, coef, sumsxf);
    // qs = sent @ Watt * (1/sqrt(200))   [MFMA, 2 blocks]
    k_mmf    <<<BG / MROWS, 512, 0, stream>>>(sent, Bpk + (size_t)5 * matstride, nullptr, qs,
                                              0, nullptr, 0.f, nullptr, nullptr, 0.07071067811865475f);
    k_combos1<<<NCT, 256, 0, stream>>>(We1, be1, hist, ntcnt, h1v, bn1);
    k_combos2<<<NCT, 256, 0, stream>>>(h1v, bn1, ge1, bte1, We2, be2, embE, embS);
    k_combos3<<<NC, 256, 0, stream>>>(embE, sumsxf, tcnt, Wa1, ba1, hist, h2pre, bn2);
    k_combos4<<<NC, 256, 0, stream>>>(h2pre, bn2, ga1, bta1, Wa2, ba2, Rc, RcT);
    k_attn   <<<BG, 512, 0, stream>>>(qs, Rc, RcT, hcnt, updS);
    // GK/GM = [upd; embS; 0-pad] @ {Wk[D:], Wm[D:]} + bias   [MFMA, 3 blocks each]
    k_mmf    <<<3, 512, 0, stream>>>(updS, Bpk + (size_t)6 * matstride, bk, GK,
                                     0, nullptr, 0.f, nullptr, nullptr, 1.f);
    k_mmf    <<<3, 512, 0, stream>>>(updS, Bpk + (size_t)7 * matstride, bm, GM,
                                     0, nullptr, 0.f, nullptr, nullptr, 1.f);
    k_mmf3   <<<NN / MROWS, 512, 0, stream>>>(x, Bpk, bq, XK, XM, XQ);
    k_soft   <<<NN / 4, 256, 0, stream>>>(ei, nt, soff_, slist, outdeg, XQ, XK, GK, SK, sc, scale);
    k_aggr   <<<NN / 4, 256, 0, stream>>>(ei, nt, doff_, dlist, sc, scale, XM, GM, SM, aggr);
    k_mmf    <<<NN / MROWS, 512, 0, stream>>>(aggr, Bpk + (size_t)3 * matstride, bo1, T1,
                                              0, nullptr, 0.f, nullptr, nullptr, 1.f);
    k_colstats<<<NN / 256, 256, 0, stream>>>(T1, bn3);
    k_mmf    <<<NN / MROWS, 512, 0, stream>>>(T1, Bpk + (size_t)4 * matstride, bo2, (float*)d_out,
                                              1, bn3, 1.f / (float)NN, go1, bto1, 1.f);
}

// Round 12
// 850.709 us; speedup vs baseline: 1.0324x; 1.0324x over previous
//
#include <hip/hip_runtime.h>

#define D     200
#define H     4
#define DH    50
#define NE    38
#define NTY   4
#define NC    608      // edge combos = 38*4*4
#define NCT   612      // + 4 self combos
#define BG    256      // graphs
#define LG    1024     // edges per graph
#define EE    262144   // E
#define NN    51200    // N
#define EA    313344   // E + N
#define NB    200      // scan blocks = NN/256

#define NTILES 13      // ceil(200/16)
#define KSTEPS 7       // ceil(200/32)
#define NMATS  8       // Wk[:D], Wm[:D], Wq, Wo1, Wo2, Watt, Wk[D:], Wm[D:]
#define SLICE_SHORTS 13312   // one K-slice: 13 nt * 1024 shorts = 26624 B
#define NCHUNK 26            // 1KB chunks per slice
#define MROWS  128           // rows per GEMM block (8 waves x 16)

typedef __attribute__((ext_vector_type(4))) float  f32x4;
typedef __attribute__((ext_vector_type(8))) short  bf16x8;

__device__ __forceinline__ short bf_hi(float f) {
    unsigned u = __float_as_uint(f);
    unsigned r = u + 0x7fffu + ((u >> 16) & 1u);
    return (short)(r >> 16);
}
__device__ __forceinline__ float bf_f(short s) {
    return __uint_as_float(((unsigned)(unsigned short)s) << 16);
}

// ---------------- per-graph combo hist (LDS, no global atomics) + degrees + coef ----------------
__global__ __launch_bounds__(256) void k_hist(const int* __restrict__ ei, const int* __restrict__ et,
                                              const int* __restrict__ nt, int* outdeg, int* indeg,
                                              int* __restrict__ hcnt, float* coef) {
    __shared__ int loc[NC];
    int g = blockIdx.x, t = threadIdx.x;
    for (int i = t; i < NC; i += 256) loc[i] = 0;
    __syncthreads();
    #pragma unroll
    for (int j = 0; j < 4; j++) {
        int e = g * LG + j * 256 + t;
        int s = ei[e], d = ei[EE + e], tp = et[e];
        int c = tp * 16 + nt[s] * 4 + nt[d];
        atomicAdd(&loc[c], 1);
        atomicAdd(&outdeg[s], 1);
        atomicAdd(&indeg[d], 1);
        unsafeAtomicAdd(&coef[(size_t)d * NE + tp],  1.f);
        unsafeAtomicAdd(&coef[(size_t)s * NE + tp], -1.f);
    }
    __syncthreads();
    for (int i = t; i < NC; i += 256) hcnt[g * NC + i] = loc[i];
}

// hist[c] = sum_g hcnt[g*NC + c]  (coalesced column sums)
__global__ __launch_bounds__(256) void k_hist2(const int* __restrict__ hcnt, int* __restrict__ hist) {
    int c = blockIdx.x * 256 + threadIdx.x;
    if (c >= NC) return;
    int s = 0;
    for (int g = 0; g < BG; g++) s += hcnt[g * NC + c];
    hist[c] = s;
}

__global__ __launch_bounds__(256) void k_ntcnt(const int* __restrict__ nt, int* ntcnt) {
    __shared__ int loc[NTY];
    int t = threadIdx.x;
    if (t < NTY) loc[t] = 0;
    __syncthreads();
    int n = blockIdx.x * 256 + t;
    if (n < NN) atomicAdd(&loc[nt[n]], 1);
    __syncthreads();
    if (t < NTY) atomicAdd(&ntcnt[t], loc[t]);
}

__global__ void k_tcnt(const int* __restrict__ hist, int* tcnt) {
    int t = threadIdx.x;
    if (t < NE) { int s = 0; for (int i = 0; i < 16; i++) s += hist[t*16 + i]; tcnt[t] = s; }
}

// sums = coef^T (38 x NN) @ x (NN x 200), K-split GEMM.
__global__ __launch_bounds__(256) void k_xfsum3(const float* __restrict__ x, const float* __restrict__ coef,
                                                float* sums) {
    const int CH = NN / 256;   // 200 nodes per block
    int t = threadIdx.x;
    int n0 = blockIdx.x * CH;
    float acc[NE];
    #pragma unroll
    for (int m = 0; m < NE; m++) acc[m] = 0.f;
    if (t < D) {
        for (int k = 0; k < CH; k++) {
            int n = n0 + k;
            float xv = x[(size_t)n * D + t];
            const float* cf = coef + (size_t)n * NE;
            #pragma unroll
            for (int m = 0; m < NE; m++) acc[m] += cf[m] * xv;
        }
        #pragma unroll
        for (int m = 0; m < NE; m++)
            if (acc[m] != 0.f) unsafeAtomicAdd(&sums[m * D + t], acc[m]);
    }
}

// ---------------- CSR build: 3-phase parallel scan + scatter ----------------
__global__ __launch_bounds__(256) void k_scan_a(const int* __restrict__ a, const int* __restrict__ b,
                                                int* bsA, int* bsB) {
    __shared__ int redA[4], redB[4];
    int t = threadIdx.x, blk = blockIdx.x;
    int i = blk * 256 + t;
    int va = a[i], vb = b[i];
    for (int o = 1; o < 64; o <<= 1) { va += __shfl_xor(va, o); vb += __shfl_xor(vb, o); }
    int wave = t >> 6, lane = t & 63;
    if (lane == 0) { redA[wave] = va; redB[wave] = vb; }
    __syncthreads();
    if (t == 0) {
        bsA[blk] = redA[0] + redA[1] + redA[2] + redA[3];
        bsB[blk] = redB[0] + redB[1] + redB[2] + redB[3];
    }
}

__global__ __launch_bounds__(256) void k_scan_b(int* bsA, int* bsB, int* aoff, int* boff) {
    __shared__ int pa[256], pb[256];
    int t = threadIdx.x;
    int va = (t < NB) ? bsA[t] : 0;
    int vb = (t < NB) ? bsB[t] : 0;
    pa[t] = va; pb[t] = vb;
    __syncthreads();
    for (int off = 1; off < 256; off <<= 1) {
        int xa = (t >= off) ? pa[t - off] : 0;
        int xb = (t >= off) ? pb[t - off] : 0;
        __syncthreads();
        pa[t] += xa; pb[t] += xb;
        __syncthreads();
    }
    if (t < NB) { bsA[t] = pa[t] - va; bsB[t] = pb[t] - vb; }
    if (t == NB - 1) { aoff[NN] = pa[t]; boff[NN] = pb[t]; }
}

__global__ __launch_bounds__(256) void k_scan_c(const int* __restrict__ a, const int* __restrict__ b,
                                                const int* __restrict__ bsA, const int* __restrict__ bsB,
                                                int* aoff, int* boff, int* acur, int* bcur) {
    __shared__ int wsA[4], wsB[4];
    int t = threadIdx.x, blk = blockIdx.x;
    int i = blk * 256 + t;
    int va = a[i], vb = b[i];
    int wave = t >> 6, lane = t & 63;
    int sa = va, sb = vb;
    for (int o = 1; o < 64; o <<= 1) {
        int xa = __shfl_up(sa, o);
        int xb = __shfl_up(sb, o);
        if (lane >= o) { sa += xa; sb += xb; }
    }
    if (lane == 63) { wsA[wave] = sa; wsB[wave] = sb; }
    __syncthreads();
    int baseA = bsA[blk], baseB = bsB[blk];
    #pragma unroll
    for (int wv = 0; wv < 3; wv++) {
        if (wv < wave) { baseA += wsA[wv]; baseB += wsB[wv]; }
    }
    int ea = baseA + sa - va;   // exclusive
    int eb = baseB + sb - vb;
    aoff[i] = ea; acur[i] = ea;
    boff[i] = eb; bcur[i] = eb;
}

__global__ __launch_bounds__(256) void k_scatter(const int* __restrict__ ei, int* scur, int* dcur,
                                                 int* slist, int* dlist) {
    int e = blockIdx.x * 256 + threadIdx.x;
    if (e >= EE) return;
    int s = ei[e], d = ei[EE + e];
    slist[atomicAdd(&scur[s], 1)] = e;
    dlist[atomicAdd(&dcur[d], 1)] = e;
}

// ---------------- per-combo MLP pipeline ----------------
__global__ __launch_bounds__(256) void k_combos1(const float* __restrict__ We1, const float* __restrict__ be1,
                                                 const int* __restrict__ hist, const int* __restrict__ ntcnt,
                                                 float* __restrict__ h1, float* bn1) {
    int c = blockIdx.x, d = threadIdx.x;
    if (d >= D) return;
    float v, w;
    if (c < NC) {
        int etp = c >> 4, ts = (c >> 2) & 3, td = c & 3;
        v = We1[etp*D + d] + We1[(39+ts)*D + d] + We1[(43+td)*D + d] + be1[d];
        w = (float)hist[c];
    } else {
        int t = c - NC;
        v = We1[38*D + d] + We1[(39+t)*D + d] + We1[(43+t)*D + d] + be1[d];
        w = (float)ntcnt[t];
    }
    h1[c*D + d] = v;
    unsafeAtomicAdd(&bn1[d], w * v);
    unsafeAtomicAdd(&bn1[D + d], w * v * v);
}

__global__ __launch_bounds__(256) void k_combos2(const float* __restrict__ h1, const float* __restrict__ bn1,
                                                 const float* __restrict__ ge1, const float* __restrict__ bte1,
                                                 const float* __restrict__ We2, const float* __restrict__ be2,
                                                 float* __restrict__ embE, float* __restrict__ embS) {
    __shared__ float v[D];
    int c = blockIdx.x, t = threadIdx.x;
    if (t < D) {
        float cnt = (float)(EE + NN);
        float m = bn1[t] / cnt;
        float var = bn1[D + t] / cnt - m * m;
        float r = rsqrtf(var + 1e-5f);
        float u = (h1[c*D + t] - m) * r * ge1[t] + bte1[t];
        v[t] = fmaxf(u, 0.f);
    }
    __syncthreads();
    if (t < D) {
        float acc = be2[t];
        for (int k = 0; k < D; k++) acc += v[k] * We2[k*D + t];
        if (c < NC) embE[c*D + t] = acc; else embS[(c-NC)*D + t] = acc;
    }
}

__global__ __launch_bounds__(256) void k_combos3(const float* __restrict__ embE, const float* __restrict__ sumsxf,
                                                 const int* __restrict__ tcnt, const float* __restrict__ Wa1,
                                                 const float* __restrict__ ba1, const int* __restrict__ hist,
                                                 float* __restrict__ h2, float* bn2) {
    __shared__ float a[2*D];
    int c = blockIdx.x, t = threadIdx.x;
    int etp = c >> 4;
    if (t < D) {
        a[t] = embE[c*D + t];
        float cn = fmaxf((float)tcnt[etp], 1.f);
        a[D + t] = sumsxf[etp*D + t] / cn;
    }
    __syncthreads();
    if (t < D) {
        float acc = ba1[t];
        for (int k = 0; k < 2*D; k++) acc += a[k] * Wa1[k*D + t];
        h2[c*D + t] = acc;
        float w = (float)hist[c];
        unsafeAtomicAdd(&bn2[t], w * acc);
        unsafeAtomicAdd(&bn2[D + t], w * acc * acc);
    }
}

// also writes RcT (200 x 608) for the coalesced attention score pass
__global__ __launch_bounds__(256) void k_combos4(const float* __restrict__ h2, const float* __restrict__ bn2,
                                                 const float* __restrict__ ga1, const float* __restrict__ bta1,
                                                 const float* __restrict__ Wa2, const float* __restrict__ ba2,
                                                 float* __restrict__ Rc, float* __restrict__ RcT) {
    __shared__ float v[D];
    int c = blockIdx.x, t = threadIdx.x;
    if (t < D) {
        float inv = 1.f / (float)EE;
        float m = bn2[t] * inv;
        float var = bn2[D + t] * inv - m * m;
        float r = rsqrtf(var + 1e-5f);
        float u = (h2[c*D + t] - m) * r * ga1[t] + bta1[t];
        v[t] = fmaxf(u, 0.f);
    }
    __syncthreads();
    if (t < D) {
        float acc = ba2[t];
        for (int k = 0; k < D; k++) acc += v[k] * Wa2[k*D + t];
        Rc[c*D + t] = acc;
        RcT[(size_t)t * NC + c] = acc;
    }
}

// ---------------- per-graph attention: qs precomputed by MFMA, 8-wave latency-hiding ----------------
__global__ __launch_bounds__(512) void k_attn(const float* __restrict__ qs,
                                              const float* __restrict__ Rc, const float* __restrict__ RcT,
                                              const int* __restrict__ hcnt, float* __restrict__ upd) {
    __shared__ float q[D];
    __shared__ float w[NC];
    __shared__ float red[16];
    __shared__ float part[8][D];
    int b = blockIdx.x, t = threadIdx.x;
    int wave = t >> 6, lane = t & 63;
    if (t < D) q[t] = qs[b*D + t];   // already scaled by 1/sqrt(200)
    __syncthreads();
    {
        float s0a = 0.f, s0b = 0.f, s0c = 0.f, s0d = 0.f;
        float s1a = 0.f, s1b = 0.f, s1c = 0.f, s1d = 0.f;
        for (int k = 0; k < D; k += 4) {
            float q0 = q[k], q1 = q[k+1], q2 = q[k+2], q3 = q[k+3];
            const float* r = RcT + (size_t)k * NC;
            s0a += q0 * r[t];
            s0b += q1 * r[NC + t];
            s0c += q2 * r[2*NC + t];
            s0d += q3 * r[3*NC + t];
            if (t < NC - 512) {
                s1a += q0 * r[t + 512];
                s1b += q1 * r[NC + t + 512];
                s1c += q2 * r[2*NC + t + 512];
                s1d += q3 * r[3*NC + t + 512];
            }
        }
        w[t] = (s0a + s0b) + (s0c + s0d);
        if (t < NC - 512) w[t + 512] = (s1a + s1b) + (s1c + s1d);
    }
    __syncthreads();
    float mx = -1e30f;
    for (int c = t; c < NC; c += 512) mx = fmaxf(mx, w[c]);
    for (int o = 32; o; o >>= 1) mx = fmaxf(mx, __shfl_xor(mx, o));
    if (lane == 0) red[wave] = mx;
    __syncthreads();
    mx = red[0];
    #pragma unroll
    for (int i = 1; i < 8; i++) mx = fmaxf(mx, red[i]);
    float sm = 0.f;
    for (int c = t; c < NC; c += 512) {
        float wv = (float)hcnt[b * NC + c] * __expf(w[c] - mx);
        w[c] = wv;
        sm += wv;
    }
    for (int o = 32; o; o >>= 1) sm += __shfl_xor(sm, o);
    if (lane == 0) red[8 + wave] = sm;
    __syncthreads();
    float tot = red[8];
    #pragma unroll
    for (int i = 1; i < 8; i++) tot += red[8 + i];
    float inv = 1.f / tot;
    float a4[4] = {0.f, 0.f, 0.f, 0.f};
    for (int c = wave * (NC/8); c < (wave + 1) * (NC/8); c++) {
        float wv = w[c];
        const float* r = Rc + c * D;
        #pragma unroll
        for (int j = 0; j < 4; j++) { int dd = lane + 64*j; if (dd < D) a4[j] += wv * r[dd]; }
    }
    #pragma unroll
    for (int j = 0; j < 4; j++) { int dd = lane + 64*j; if (dd < D) part[wave][dd] = a4[j]; }
    __syncthreads();
    if (t < D) {
        float s = part[0][t];
        #pragma unroll
        for (int i = 1; i < 8; i++) s += part[i][t];
        upd[b*D + t] = s * inv;
    }
}

// ---------------- weight packing: ks-major slices, B-fragment order, bf16 hi/lo ----------------
// blk = mat*91 + ks*13 + nt; each (mat,ks) slice = 26624 B contiguous.
// mats: 0=Wk[:D] 1=Wm[:D] 2=Wq 3=Wo1 4=Wo2 5=Watt 6=Wk[D:] 7=Wm[D:]
__global__ __launch_bounds__(256) void k_packW(const float* __restrict__ Wk, const float* __restrict__ Wm,
                                               const float* __restrict__ Wq, const float* __restrict__ Wo1,
                                               const float* __restrict__ Wo2, const float* __restrict__ Watt,
                                               short* __restrict__ Bpk) {
    int blk = blockIdx.x;
    int mat = blk / (NTILES * KSTEPS);
    int rem = blk - mat * (NTILES * KSTEPS);
    int ks = rem / NTILES, nt = rem - ks * NTILES;
    const float* W = (mat == 0) ? Wk : (mat == 1) ? Wm : (mat == 2) ? Wq : (mat == 3) ? Wo1 :
                     (mat == 4) ? Wo2 : (mat == 5) ? Watt : (mat == 6) ? (Wk + D*D) : (Wm + D*D);
    int t = threadIdx.x;
    for (int idx = t; idx < 1024; idx += 256) {
        int split = idx >> 9;
        int lane = (idx & 511) >> 3;
        int j = idx & 7;
        int n = nt * 16 + (lane & 15);
        int k = ks * 32 + ((lane >> 4) << 3) + j;
        float v = (k < D && n < D) ? W[k * D + n] : 0.f;
        short h = bf_hi(v);
        short out = split ? bf_hi(v - bf_f(h)) : h;
        Bpk[(size_t)blk * 1024 + idx] = out;
    }
}

// ---------------- MFMA GEMM core (512 threads, 128 rows, A-frags hoisted) ----------------
__device__ __forceinline__ void stage_load8(const short* __restrict__ g, int w, int lane, f32x4 rg[4]) {
    #pragma unroll
    for (int i = 0; i < 4; i++) {
        int c = w + 8 * i;
        if (c < NCHUNK) rg[i] = *(const f32x4*)((const char*)g + c * 1024 + lane * 16);
    }
}
__device__ __forceinline__ void stage_write8(short* l, int w, int lane, const f32x4 rg[4]) {
    #pragma unroll
    for (int i = 0; i < 4; i++) {
        int c = w + 8 * i;
        if (c < NCHUNK) *(f32x4*)((char*)l + c * 1024 + lane * 16) = rg[i];
    }
}

__device__ __forceinline__ void load_afrag(const float* __restrict__ A, int row, int quad, int ks,
                                           int preop, const float* __restrict__ bnacc, float invCnt,
                                           const float* __restrict__ g, const float* __restrict__ bb,
                                           bf16x8& ah, bf16x8& al) {
    int k0 = ks * 32 + quad * 8;
    float v[8];
    if (k0 < D) {   // k0 multiple of 8 < 200 => k0+8 <= 200, always in-row
        const float* src = A + (size_t)row * D + k0;
        float4 p0 = *(const float4*)src;
        float4 p1 = *(const float4*)(src + 4);
        v[0]=p0.x; v[1]=p0.y; v[2]=p0.z; v[3]=p0.w;
        v[4]=p1.x; v[5]=p1.y; v[6]=p1.z; v[7]=p1.w;
        if (preop) {
            float4 m0 = *(const float4*)(bnacc + k0);
            float4 m1 = *(const float4*)(bnacc + k0 + 4);
            float4 q0 = *(const float4*)(bnacc + D + k0);
            float4 q1 = *(const float4*)(bnacc + D + k0 + 4);
            float4 g0 = *(const float4*)(g + k0);
            float4 g1 = *(const float4*)(g + k0 + 4);
            float4 b0 = *(const float4*)(bb + k0);
            float4 b1 = *(const float4*)(bb + k0 + 4);
            float mm[8] = {m0.x,m0.y,m0.z,m0.w,m1.x,m1.y,m1.z,m1.w};
            float qq[8] = {q0.x,q0.y,q0.z,q0.w,q1.x,q1.y,q1.z,q1.w};
            float gg[8] = {g0.x,g0.y,g0.z,g0.w,g1.x,g1.y,g1.z,g1.w};
            float bv[8] = {b0.x,b0.y,b0.z,b0.w,b1.x,b1.y,b1.z,b1.w};
            #pragma unroll
            for (int j = 0; j < 8; j++) {
                float mj = mm[j] * invCnt;
                float var = qq[j] * invCnt - mj * mj;
                float rs = rsqrtf(var + 1e-5f);
                float s = rs * gg[j];
                v[j] = fmaxf(v[j] * s + (bv[j] - mj * s), 0.f);
            }
        }
    } else {
        #pragma unroll
        for (int j = 0; j < 8; j++) v[j] = 0.f;
    }
    #pragma unroll
    for (int j = 0; j < 8; j++) {
        short h = bf_hi(v[j]);
        ah[j] = h;
        al[j] = bf_hi(v[j] - bf_f(h));
    }
}

__device__ __forceinline__ void store_C(f32x4 acc[NTILES], float* __restrict__ C, int n0, int w, int lane,
                                        const float* __restrict__ bias, float postscale) {
    int colb = lane & 15, quad = lane >> 4;
    #pragma unroll
    for (int nt = 0; nt < NTILES; nt++) {
        int col = nt * 16 + colb;
        if (col < D) {
            float bj = bias ? bias[col] : 0.f;
            #pragma unroll
            for (int r = 0; r < 4; r++) {
                int row = n0 + w * 16 + quad * 4 + r;
                C[(size_t)row * D + col] = (acc[nt][r] + bj) * postscale;
            }
        }
    }
}

// one K-step: prefetch slice u+1, MFMA slice u from LDS, write prefetched, barrier.
// AH/AL are NAMED per-ks registers (static indexing, no scratch).
#define MMF_KS(MATV, KS, AH, AL, NUTOT, BASE)                                   \
    {                                                                           \
        int u_ = (MATV) * KSTEPS + (KS);                                        \
        int cur_ = u_ & 1;                                                      \
        if (u_ + 1 < (NUTOT))                                                   \
            stage_load8((BASE) + (size_t)(u_ + 1) * SLICE_SHORTS, w, lane, rg); \
        const bf16x8* B8_ = (const bf16x8*)(Bls + cur_ * SLICE_SHORTS);         \
        _Pragma("unroll")                                                       \
        for (int nt = 0; nt < NTILES; nt++) {                                   \
            bf16x8 bh = B8_[nt * 128 + lane];                                   \
            bf16x8 bl = B8_[nt * 128 + 64 + lane];                              \
            acc[nt] = __builtin_amdgcn_mfma_f32_16x16x32_bf16(AL, bh, acc[nt], 0, 0, 0); \
            acc[nt] = __builtin_amdgcn_mfma_f32_16x16x32_bf16(AH, bl, acc[nt], 0, 0, 0); \
            acc[nt] = __builtin_amdgcn_mfma_f32_16x16x32_bf16(AH, bh, acc[nt], 0, 0, 0); \
        }                                                                       \
        if (u_ + 1 < (NUTOT)) {                                                 \
            stage_write8(Bls + (cur_ ^ 1) * SLICE_SHORTS, w, lane, rg);         \
            __syncthreads();                                                    \
        }                                                                       \
    }

// ---------------- fused x @ {Wk[:D], Wm[:D], Wq} ----------------
__global__ __launch_bounds__(512, 2) void k_mmf3(const float* __restrict__ A, const short* __restrict__ Bpk,
                                                 const float* __restrict__ bq,
                                                 float* __restrict__ XK, float* __restrict__ XM, float* __restrict__ XQ) {
    __shared__ __align__(16) short Bls[2 * SLICE_SHORTS];   // 53248 B
    int t = threadIdx.x, w = t >> 6, lane = t & 63;
    int n0 = blockIdx.x * MROWS;
    int row = n0 + w * 16 + (lane & 15);
    int quad = lane >> 4;
    // A fragments loaded + converted ONCE, reused for all 3 mats
    bf16x8 ah0, al0, ah1, al1, ah2, al2, ah3, al3, ah4, al4, ah5, al5, ah6, al6;
    load_afrag(A, row, quad, 0, 0, nullptr, 0.f, nullptr, nullptr, ah0, al0);
    load_afrag(A, row, quad, 1, 0, nullptr, 0.f, nullptr, nullptr, ah1, al1);
    load_afrag(A, row, quad, 2, 0, nullptr, 0.f, nullptr, nullptr, ah2, al2);
    load_afrag(A, row, quad, 3, 0, nullptr, 0.f, nullptr, nullptr, ah3, al3);
    load_afrag(A, row, quad, 4, 0, nullptr, 0.f, nullptr, nullptr, ah4, al4);
    load_afrag(A, row, quad, 5, 0, nullptr, 0.f, nullptr, nullptr, ah5, al5);
    load_afrag(A, row, quad, 6, 0, nullptr, 0.f, nullptr, nullptr, ah6, al6);
    f32x4 rg[4];
    stage_load8(Bpk, w, lane, rg);
    stage_write8(Bls, w, lane, rg);
    __syncthreads();
    f32x4 acc[NTILES];
    for (int mat = 0; mat < 3; ++mat) {
        #pragma unroll
        for (int nt = 0; nt < NTILES; nt++) { acc[nt][0]=0.f; acc[nt][1]=0.f; acc[nt][2]=0.f; acc[nt][3]=0.f; }
        MMF_KS(mat, 0, ah0, al0, 3*KSTEPS, Bpk)
        MMF_KS(mat, 1, ah1, al1, 3*KSTEPS, Bpk)
        MMF_KS(mat, 2, ah2, al2, 3*KSTEPS, Bpk)
        MMF_KS(mat, 3, ah3, al3, 3*KSTEPS, Bpk)
        MMF_KS(mat, 4, ah4, al4, 3*KSTEPS, Bpk)
        MMF_KS(mat, 5, ah5, al5, 3*KSTEPS, Bpk)
        MMF_KS(mat, 6, ah6, al6, 3*KSTEPS, Bpk)
        if (mat == 0)      store_C(acc, XK, n0, w, lane, nullptr, 1.f);
        else if (mat == 1) store_C(acc, XM, n0, w, lane, nullptr, 1.f);
        else               store_C(acc, XQ, n0, w, lane, bq, 0.14142135623730950488f);
    }
}

// ---------------- generic MFMA matmul (one B), optional BN+relu preop ----------------
__global__ __launch_bounds__(512, 2) void k_mmf(const float* __restrict__ A, const short* __restrict__ Bmat,
                                                const float* __restrict__ bias, float* __restrict__ C,
                                                int preop, const float* __restrict__ bnacc, float invCnt,
                                                const float* __restrict__ g, const float* __restrict__ bb,
                                                float postscale) {
    __shared__ __align__(16) short Bls[2 * SLICE_SHORTS];
    int t = threadIdx.x, w = t >> 6, lane = t & 63;
    int n0 = blockIdx.x * MROWS;
    int row = n0 + w * 16 + (lane & 15);
    int quad = lane >> 4;
    bf16x8 ah0, al0, ah1, al1, ah2, al2, ah3, al3, ah4, al4, ah5, al5, ah6, al6;
    load_afrag(A, row, quad, 0, preop, bnacc, invCnt, g, bb, ah0, al0);
    load_afrag(A, row, quad, 1, preop, bnacc, invCnt, g, bb, ah1, al1);
    load_afrag(A, row, quad, 2, preop, bnacc, invCnt, g, bb, ah2, al2);
    load_afrag(A, row, quad, 3, preop, bnacc, invCnt, g, bb, ah3, al3);
    load_afrag(A, row, quad, 4, preop, bnacc, invCnt, g, bb, ah4, al4);
    load_afrag(A, row, quad, 5, preop, bnacc, invCnt, g, bb, ah5, al5);
    load_afrag(A, row, quad, 6, preop, bnacc, invCnt, g, bb, ah6, al6);
    f32x4 rg[4];
    stage_load8(Bmat, w, lane, rg);
    stage_write8(Bls, w, lane, rg);
    __syncthreads();
    f32x4 acc[NTILES];
    #pragma unroll
    for (int nt = 0; nt < NTILES; nt++) { acc[nt][0]=0.f; acc[nt][1]=0.f; acc[nt][2]=0.f; acc[nt][3]=0.f; }
    MMF_KS(0, 0, ah0, al0, KSTEPS, Bmat)
    MMF_KS(0, 1, ah1, al1, KSTEPS, Bmat)
    MMF_KS(0, 2, ah2, al2, KSTEPS, Bmat)
    MMF_KS(0, 3, ah3, al3, KSTEPS, Bmat)
    MMF_KS(0, 4, ah4, al4, KSTEPS, Bmat)
    MMF_KS(0, 5, ah5, al5, KSTEPS, Bmat)
    MMF_KS(0, 6, ah6, al6, KSTEPS, Bmat)
    store_C(acc, C, n0, w, lane, bias, postscale);
}

// 7-shuffle reduce-scatter: input 4 head partials/lane; output: lane group g (lane>>4) holds head-g total
__device__ __forceinline__ float head_reduce(float h0, float h1, float h2, float h3, int lane) {
    float ax = (lane < 32) ? h2 : h0;
    float ay = (lane < 32) ? h3 : h1;
    float u0 = ((lane < 32) ? h0 : h2) + __shfl_xor(ax, 32);
    float u1 = ((lane < 32) ? h1 : h3) + __shfl_xor(ay, 32);
    float bx = ((lane & 16) == 0) ? u1 : u0;
    float v  = (((lane & 16) == 0) ? u0 : u1) + __shfl_xor(bx, 16);
    v += __shfl_xor(v, 8);
    v += __shfl_xor(v, 4);
    v += __shfl_xor(v, 2);
    v += __shfl_xor(v, 1);
    return v;
}

// ---------------- edge softmax, src-CSR, wave per node; d = head*50 + lane ----------------
__global__ __launch_bounds__(256) void k_soft(const int* __restrict__ ei, const int* __restrict__ nt,
                                              const int* __restrict__ soff, const int* __restrict__ slist,
                                              const int* __restrict__ outdeg,
                                              const float* __restrict__ XQ, const float* __restrict__ XK,
                                              const float* __restrict__ GK, const float* __restrict__ SK,
                                              float* __restrict__ sc, float* __restrict__ scale) {
    int wave = threadIdx.x >> 6, lane = threadIdx.x & 63;
    int n = blockIdx.x * 4 + wave;
    if (n >= NN) return;
    bool act = lane < DH;
    int grp = lane >> 4;
    float qv0 = 0.f, qv1 = 0.f, qv2 = 0.f, qv3 = 0.f;
    if (act) {
        const float* q = XQ + (size_t)n * D + lane;
        qv0 = q[0]; qv1 = q[DH]; qv2 = q[2*DH]; qv3 = q[3*DH];
    }
    float den = 0.f;
    {   // self edge
        int tn = nt[n];
        float h0 = 0.f, h1 = 0.f, h2 = 0.f, h3 = 0.f;
        if (act) {
            const float* xk = XK + (size_t)n * D + lane;
            const float* sk = SK + (size_t)tn * D + lane;
            h0 = qv0 * (xk[0]    + sk[0]);
            h1 = qv1 * (xk[DH]   + sk[DH]);
            h2 = qv2 * (xk[2*DH] + sk[2*DH]);
            h3 = qv3 * (xk[3*DH] + sk[3*DH]);
        }
        float v = head_reduce(h0, h1, h2, h3, lane);
        float e = __expf(v);
        den += e;
        if ((lane & 15) == 0) sc[(size_t)(EE + n) * 4 + grp] = e;
    }
    int beg = soff[n], end = soff[n + 1];
    for (int i = beg; i < end; i++) {
        int e_ = slist[i];
        int tail = ei[EE + e_];
        int g = e_ >> 10;
        float h0 = 0.f, h1 = 0.f, h2 = 0.f, h3 = 0.f;
        if (act) {
            const float* xk = XK + (size_t)tail * D + lane;
            const float* gk = GK + (size_t)g * D + lane;
            h0 = qv0 * (xk[0]    + gk[0]);
            h1 = qv1 * (xk[DH]   + gk[DH]);
            h2 = qv2 * (xk[2*DH] + gk[2*DH]);
            h3 = qv3 * (xk[3*DH] + gk[3*DH]);
        }
        float v = head_reduce(h0, h1, h2, h3, lane);
        float e = __expf(v);
        den += e;
        if ((lane & 15) == 0) sc[(size_t)e_ * 4 + grp] = e;
    }
    float cnt = (float)(outdeg[n] + 1);
    if ((lane & 15) == 0) scale[(size_t)n * 4 + grp] = cnt / den;
}

// ---------------- aggregation, dst-CSR, wave per node; d = head*50 + lane ----------------
__global__ __launch_bounds__(256) void k_aggr(const int* __restrict__ ei, const int* __restrict__ nt,
                                              const int* __restrict__ doff, const int* __restrict__ dlist,
                                              const float* __restrict__ sc, const float* __restrict__ scale,
                                              const float* __restrict__ XM, const float* __restrict__ GM,
                                              const float* __restrict__ SM, float* __restrict__ aggr) {
    int wave = threadIdx.x >> 6, lane = threadIdx.x & 63;
    int n = blockIdx.x * 4 + wave;
    if (n >= NN) return;
    bool act = lane < DH;
    float acc0 = 0.f, acc1 = 0.f, acc2 = 0.f, acc3 = 0.f;
    {   // self edge
        int tn = nt[n];
        float4 ss = *(const float4*)&sc[(size_t)(EE + n) * 4];
        float4 sl = *(const float4*)&scale[(size_t)n * 4];
        if (act) {
            const float* xm = XM + (size_t)n * D + lane;
            const float* sm = SM + (size_t)tn * D + lane;
            acc0 += ss.x * sl.x * (xm[0]    + sm[0]);
            acc1 += ss.y * sl.y * (xm[DH]   + sm[DH]);
            acc2 += ss.z * sl.z * (xm[2*DH] + sm[2*DH]);
            acc3 += ss.w * sl.w * (xm[3*DH] + sm[3*DH]);
        }
    }
    int beg = doff[n], end = doff[n + 1];
    for (int i = beg; i < end; i++) {
        int e = dlist[i];
        int s = ei[e];
        int g = e >> 10;
        float4 ss = *(const float4*)&sc[(size_t)e * 4];
        float4 sl = *(const float4*)&scale[(size_t)s * 4];
        if (act) {
            const float* xm = XM + (size_t)s * D + lane;
            const float* gm = GM + (size_t)g * D + lane;
            acc0 += ss.x * sl.x * (xm[0]    + gm[0]);
            acc1 += ss.y * sl.y * (xm[DH]   + gm[DH]);
            acc2 += ss.z * sl.z * (xm[2*DH] + gm[2*DH]);
            acc3 += ss.w * sl.w * (xm[3*DH] + gm[3*DH]);
        }
    }
    if (act) {
        float* out = aggr + (size_t)n * D + lane;
        out[0]    = acc0;
        out[DH]   = acc1;
        out[2*DH] = acc2;
        out[3*DH] = acc3;
    }
}

// ---------------- column stats for final BN ----------------
__global__ __launch_bounds__(256) void k_colstats(const float* __restrict__ T1, float* bn3) {
    int t = threadIdx.x;
    if (t >= D) return;
    int r0 = blockIdx.x * 256;
    float s = 0.f, q = 0.f;
    for (int r = r0; r < r0 + 256; r++) {
        float v = T1[(size_t)r * D + t];
        s += v; q += v * v;
    }
    unsafeAtomicAdd(&bn3[t], s);
    unsafeAtomicAdd(&bn3[D + t], q);
}

extern "C" void kernel_launch(void* const* d_in, const int* in_sizes, int n_in,
                              void* d_out, int out_size, void* d_ws, size_t ws_size,
                              hipStream_t stream) {
    const float* x    = (const float*)d_in[0];
    const float* sent = (const float*)d_in[2];
    const float* We1  = (const float*)d_in[3];
    const float* be1  = (const float*)d_in[4];
    const float* ge1  = (const float*)d_in[5];
    const float* bte1 = (const float*)d_in[6];
    const float* We2  = (const float*)d_in[7];
    const float* be2  = (const float*)d_in[8];
    const float* Wa1  = (const float*)d_in[9];
    const float* ba1  = (const float*)d_in[10];
    const float* ga1  = (const float*)d_in[11];
    const float* bta1 = (const float*)d_in[12];
    const float* Wa2  = (const float*)d_in[13];
    const float* ba2  = (const float*)d_in[14];
    const float* Watt = (const float*)d_in[15];
    const float* Wk   = (const float*)d_in[16];
    const float* bk   = (const float*)d_in[17];
    const float* Wm   = (const float*)d_in[18];
    const float* bm   = (const float*)d_in[19];
    const float* Wq   = (const float*)d_in[20];
    const float* bq   = (const float*)d_in[21];
    const float* Wo1  = (const float*)d_in[22];
    const float* bo1  = (const float*)d_in[23];
    const float* go1  = (const float*)d_in[24];
    const float* bto1 = (const float*)d_in[25];
    const float* Wo2  = (const float*)d_in[26];
    const float* bo2  = (const float*)d_in[27];
    const int* ei = (const int*)d_in[28];
    const int* et = (const int*)d_in[29];
    const int* nt = (const int*)d_in[30];

    char* ws = (char*)d_ws;
    size_t off = 0;
    auto alloc = [&](size_t bytes) -> char* {
        char* p = ws + off;
        off = (off + bytes + 255) & ~(size_t)255;
        return p;
    };
    // ---- zeroed region ----
    int*   hist   = (int*)  alloc(NC * 4);
    int*   ntcnt  = (int*)  alloc(NTY * 4);
    float* bn1    = (float*)alloc(2 * D * 4);
    float* bn2    = (float*)alloc(2 * D * 4);
    float* bn3    = (float*)alloc(2 * D * 4);
    float* sumsxf = (float*)alloc(NE * D * 4);
    int*   outdeg = (int*)  alloc(NN * 4);
    int*   indeg  = (int*)  alloc(NN * 4);
    int*   hcnt   = (int*)  alloc((size_t)BG * NC * 4);   // per-graph combo histogram
    float* updS   = (float*)alloc((size_t)384 * D * 4);   // rows: 0..255 upd, 256..259 embS, 260..383 pad
    size_t zero_end = off;
    // ---- rest ----
    int* tcnt = (int*)alloc(NE * 4);
    int* soff_ = (int*)alloc((NN + 1) * 4);
    int* doff_ = (int*)alloc((NN + 1) * 4);
    int* scur = (int*)alloc(NN * 4);
    int* dcur = (int*)alloc(NN * 4);
    int* bsA  = (int*)alloc(NB * 4);
    int* bsB  = (int*)alloc(NB * 4);
    int* slist = (int*)alloc((size_t)EE * 4);
    int* dlist = (int*)alloc((size_t)EE * 4);
    short* Bpk  = (short*)alloc((size_t)NMATS * NTILES * KSTEPS * 1024 * 2);   // 8 mats packed
    float* h1v   = (float*)alloc((size_t)NCT * D * 4);
    float* embE  = (float*)alloc((size_t)NC * D * 4);
    float* h2pre = (float*)alloc((size_t)NC * D * 4);
    float* Rc    = (float*)alloc((size_t)NC * D * 4);
    float* RcT   = (float*)alloc((size_t)D * NC * 4);
    float* qs    = (float*)alloc((size_t)BG * D * 4);
    float* GK    = (float*)alloc((size_t)384 * D * 4);    // rows 256..259 = SK
    float* GM    = (float*)alloc((size_t)384 * D * 4);    // rows 256..259 = SM
    float* sc    = (float*)alloc((size_t)EA * H * 4);
    float* XK    = (float*)alloc((size_t)NN * D * 4);
    float* XM    = (float*)alloc((size_t)NN * D * 4);
    float* XQ    = (float*)alloc((size_t)NN * D * 4);
    // aliases (liveness-checked):
    float* coef  = XK;            // dead before k_mmf3 writes XK
    float* scale = h1v;           // h1v dead before k_soft writes scale
    float* aggr  = XQ;            // XQ dead after k_soft
    float* T1    = XK;            // XK dead after k_soft
    float* embS  = updS + 256 * D;
    float* SK    = GK + 256 * D;
    float* SM    = GM + 256 * D;

    const int matstride = NTILES * KSTEPS * 1024;   // shorts per packed mat

    hipMemsetAsync(ws, 0, zero_end, stream);
    hipMemsetAsync(coef, 0, (size_t)NN * NE * 4, stream);

    k_packW  <<<NMATS * NTILES * KSTEPS, 256, 0, stream>>>(Wk, Wm, Wq, Wo1, Wo2, Watt, Bpk);
    k_hist   <<<BG, 256, 0, stream>>>(ei, et, nt, outdeg, indeg, hcnt, coef);
    k_hist2  <<<3, 256, 0, stream>>>(hcnt, hist);
    k_ntcnt  <<<NN / 256, 256, 0, stream>>>(nt, ntcnt);
    k_tcnt   <<<1, 64, 0, stream>>>(hist, tcnt);
    k_scan_a <<<NB, 256, 0, stream>>>(outdeg, indeg, bsA, bsB);
    k_scan_b <<<1, 256, 0, stream>>>(bsA, bsB, soff_, doff_);
    k_scan_c <<<NB, 256, 0, stream>>>(outdeg, indeg, bsA, bsB, soff_, doff_, scur, dcur);
    k_scatter<<<EE / 256, 256, 0, stream>>>(ei, scur, dcur, slist, dlist);
    k_xfsum3 <<<256, 256, 0, stream>>>(x, coef, sumsxf);
    // qs = sent @ Watt * (1/sqrt(200))   [MFMA, 2 blocks]
    k_mmf    <<<BG / MROWS, 512, 0, stream>>>(sent, Bpk + (size_t)5 * matstride, nullptr, qs,
                                              0, nullptr, 0.f, nullptr, nullptr, 0.07071067811865475f);
    k_combos1<<<NCT, 256, 0, stream>>>(We1, be1, hist, ntcnt, h1v, bn1);
    k_combos2<<<NCT, 256, 0, stream>>>(h1v, bn1, ge1, bte1, We2, be2, embE, embS);
    k_combos3<<<NC, 256, 0, stream>>>(embE, sumsxf, tcnt, Wa1, ba1, hist, h2pre, bn2);
    k_combos4<<<NC, 256, 0, stream>>>(h2pre, bn2, ga1, bta1, Wa2, ba2, Rc, RcT);
    k_attn   <<<BG, 512, 0, stream>>>(qs, Rc, RcT, hcnt, updS);
    // GK/GM = [upd; embS; 0-pad] @ {Wk[D:], Wm[D:]} + bias   [MFMA, 3 blocks each]
    k_mmf    <<<3, 512, 0, stream>>>(updS, Bpk + (size_t)6 * matstride, bk, GK,
                                     0, nullptr, 0.f, nullptr, nullptr, 1.f);
    k_mmf    <<<3, 512, 0, stream>>>(updS, Bpk + (size_t)7 * matstride, bm, GM,
                                     0, nullptr, 0.f, nullptr, nullptr, 1.f);
    k_mmf3   <<<NN / MROWS, 512, 0, stream>>>(x, Bpk, bq, XK, XM, XQ);
    k_soft   <<<NN / 4, 256, 0, stream>>>(ei, nt, soff_, slist, outdeg, XQ, XK, GK, SK, sc, scale);
    k_aggr   <<<NN / 4, 256, 0, stream>>>(ei, nt, doff_, dlist, sc, scale, XM, GM, SM, aggr);
    k_mmf    <<<NN / MROWS, 512, 0, stream>>>(aggr, Bpk + (size_t)3 * matstride, bo1, T1,
                                              0, nullptr, 0.f, nullptr, nullptr, 1.f);
    k_colstats<<<NN / 256, 256, 0, stream>>>(T1, bn3);
    k_mmf    <<<NN / MROWS, 512, 0, stream>>>(T1, Bpk + (size_t)4 * matstride, bo2, (float*)d_out,
                                              1, bn3, 1.f / (float)NN, go1, bto1, 1.f);
}

// Round 13
// 824.809 us; speedup vs baseline: 1.0648x; 1.0314x over previous
//
#include <hip/hip_runtime.h>

#define D     200
#define H     4
#define DH    50
#define NE    38
#define NTY   4
#define NC    608      // edge combos = 38*4*4
#define NCT   612      // + 4 self combos
#define BG    256      // graphs
#define LG    1024     // edges per graph
#define EE    262144   // E
#define NN    51200    // N
#define EA    313344   // E + N
#define NB    200      // scan blocks = NN/256

#define NTILES 13      // ceil(200/16)
#define KSTEPS 7       // ceil(200/32)
#define NMATS  8       // Wk[:D], Wm[:D], Wq, Wo1, Wo2, Watt, Wk[D:], Wm[D:]
#define SLICE_SHORTS 13312   // one K-slice: 13 nt * 1024 shorts = 26624 B
#define NCHUNK 26            // 1KB chunks per slice
#define MROWS  128           // rows per GEMM block (8 waves x 16)

typedef __attribute__((ext_vector_type(4))) float  f32x4;
typedef __attribute__((ext_vector_type(8))) short  bf16x8;

__device__ __forceinline__ short bf_hi(float f) {
    unsigned u = __float_as_uint(f);
    unsigned r = u + 0x7fffu + ((u >> 16) & 1u);
    return (short)(r >> 16);
}
__device__ __forceinline__ float bf_f(short s) {
    return __uint_as_float(((unsigned)(unsigned short)s) << 16);
}

// ---------------- per-graph combo hist (LDS, no global atomics) + degrees + coef ----------------
__global__ __launch_bounds__(256) void k_hist(const int* __restrict__ ei, const int* __restrict__ et,
                                              const int* __restrict__ nt, int* outdeg, int* indeg,
                                              int* __restrict__ hcnt, float* coef) {
    __shared__ int loc[NC];
    int g = blockIdx.x, t = threadIdx.x;
    for (int i = t; i < NC; i += 256) loc[i] = 0;
    __syncthreads();
    #pragma unroll
    for (int j = 0; j < 4; j++) {
        int e = g * LG + j * 256 + t;
        int s = ei[e], d = ei[EE + e], tp = et[e];
        int c = tp * 16 + nt[s] * 4 + nt[d];
        atomicAdd(&loc[c], 1);
        atomicAdd(&outdeg[s], 1);
        atomicAdd(&indeg[d], 1);
        unsafeAtomicAdd(&coef[(size_t)d * NE + tp],  1.f);
        unsafeAtomicAdd(&coef[(size_t)s * NE + tp], -1.f);
    }
    __syncthreads();
    for (int i = t; i < NC; i += 256) hcnt[g * NC + i] = loc[i];
}

// hist[c] = sum_g hcnt[g*NC + c]  (coalesced column sums)
__global__ __launch_bounds__(256) void k_hist2(const int* __restrict__ hcnt, int* __restrict__ hist) {
    int c = blockIdx.x * 256 + threadIdx.x;
    if (c >= NC) return;
    int s = 0;
    for (int g = 0; g < BG; g++) s += hcnt[g * NC + c];
    hist[c] = s;
}

__global__ __launch_bounds__(256) void k_ntcnt(const int* __restrict__ nt, int* ntcnt) {
    __shared__ int loc[NTY];
    int t = threadIdx.x;
    if (t < NTY) loc[t] = 0;
    __syncthreads();
    int n = blockIdx.x * 256 + t;
    if (n < NN) atomicAdd(&loc[nt[n]], 1);
    __syncthreads();
    if (t < NTY) atomicAdd(&ntcnt[t], loc[t]);
}

__global__ void k_tcnt(const int* __restrict__ hist, int* tcnt) {
    int t = threadIdx.x;
    if (t < NE) { int s = 0; for (int i = 0; i < 16; i++) s += hist[t*16 + i]; tcnt[t] = s; }
}

// sums = coef^T (38 x NN) @ x (NN x 200), K-split GEMM.
__global__ __launch_bounds__(256) void k_xfsum3(const float* __restrict__ x, const float* __restrict__ coef,
                                                float* sums) {
    const int CH = NN / 256;   // 200 nodes per block
    int t = threadIdx.x;
    int n0 = blockIdx.x * CH;
    float acc[NE];
    #pragma unroll
    for (int m = 0; m < NE; m++) acc[m] = 0.f;
    if (t < D) {
        for (int k = 0; k < CH; k++) {
            int n = n0 + k;
            float xv = x[(size_t)n * D + t];
            const float* cf = coef + (size_t)n * NE;
            #pragma unroll
            for (int m = 0; m < NE; m++) acc[m] += cf[m] * xv;
        }
        #pragma unroll
        for (int m = 0; m < NE; m++)
            if (acc[m] != 0.f) unsafeAtomicAdd(&sums[m * D + t], acc[m]);
    }
}

// ---------------- CSR build: 3-phase parallel scan + scatter ----------------
__global__ __launch_bounds__(256) void k_scan_a(const int* __restrict__ a, const int* __restrict__ b,
                                                int* bsA, int* bsB) {
    __shared__ int redA[4], redB[4];
    int t = threadIdx.x, blk = blockIdx.x;
    int i = blk * 256 + t;
    int va = a[i], vb = b[i];
    for (int o = 1; o < 64; o <<= 1) { va += __shfl_xor(va, o); vb += __shfl_xor(vb, o); }
    int wave = t >> 6, lane = t & 63;
    if (lane == 0) { redA[wave] = va; redB[wave] = vb; }
    __syncthreads();
    if (t == 0) {
        bsA[blk] = redA[0] + redA[1] + redA[2] + redA[3];
        bsB[blk] = redB[0] + redB[1] + redB[2] + redB[3];
    }
}

__global__ __launch_bounds__(256) void k_scan_b(int* bsA, int* bsB, int* aoff, int* boff) {
    __shared__ int pa[256], pb[256];
    int t = threadIdx.x;
    int va = (t < NB) ? bsA[t] : 0;
    int vb = (t < NB) ? bsB[t] : 0;
    pa[t] = va; pb[t] = vb;
    __syncthreads();
    for (int off = 1; off < 256; off <<= 1) {
        int xa = (t >= off) ? pa[t - off] : 0;
        int xb = (t >= off) ? pb[t - off] : 0;
        __syncthreads();
        pa[t] += xa; pb[t] += xb;
        __syncthreads();
    }
    if (t < NB) { bsA[t] = pa[t] - va; bsB[t] = pb[t] - vb; }
    if (t == NB - 1) { aoff[NN] = pa[t]; boff[NN] = pb[t]; }
}

__global__ __launch_bounds__(256) void k_scan_c(const int* __restrict__ a, const int* __restrict__ b,
                                                const int* __restrict__ bsA, const int* __restrict__ bsB,
                                                int* aoff, int* boff, int* acur, int* bcur) {
    __shared__ int wsA[4], wsB[4];
    int t = threadIdx.x, blk = blockIdx.x;
    int i = blk * 256 + t;
    int va = a[i], vb = b[i];
    int wave = t >> 6, lane = t & 63;
    int sa = va, sb = vb;
    for (int o = 1; o < 64; o <<= 1) {
        int xa = __shfl_up(sa, o);
        int xb = __shfl_up(sb, o);
        if (lane >= o) { sa += xa; sb += xb; }
    }
    if (lane == 63) { wsA[wave] = sa; wsB[wave] = sb; }
    __syncthreads();
    int baseA = bsA[blk], baseB = bsB[blk];
    #pragma unroll
    for (int wv = 0; wv < 3; wv++) {
        if (wv < wave) { baseA += wsA[wv]; baseB += wsB[wv]; }
    }
    int ea = baseA + sa - va;   // exclusive
    int eb = baseB + sb - vb;
    aoff[i] = ea; acur[i] = ea;
    boff[i] = eb; bcur[i] = eb;
}

__global__ __launch_bounds__(256) void k_scatter(const int* __restrict__ ei, int* scur, int* dcur,
                                                 int* slist, int* dlist) {
    int e = blockIdx.x * 256 + threadIdx.x;
    if (e >= EE) return;
    int s = ei[e], d = ei[EE + e];
    slist[atomicAdd(&scur[s], 1)] = e;
    dlist[atomicAdd(&dcur[d], 1)] = e;
}

// ---------------- per-combo MLP pipeline ----------------
__global__ __launch_bounds__(256) void k_combos1(const float* __restrict__ We1, const float* __restrict__ be1,
                                                 const int* __restrict__ hist, const int* __restrict__ ntcnt,
                                                 float* __restrict__ h1, float* bn1) {
    int c = blockIdx.x, d = threadIdx.x;
    if (d >= D) return;
    float v, w;
    if (c < NC) {
        int etp = c >> 4, ts = (c >> 2) & 3, td = c & 3;
        v = We1[etp*D + d] + We1[(39+ts)*D + d] + We1[(43+td)*D + d] + be1[d];
        w = (float)hist[c];
    } else {
        int t = c - NC;
        v = We1[38*D + d] + We1[(39+t)*D + d] + We1[(43+t)*D + d] + be1[d];
        w = (float)ntcnt[t];
    }
    h1[c*D + d] = v;
    unsafeAtomicAdd(&bn1[d], w * v);
    unsafeAtomicAdd(&bn1[D + d], w * v * v);
}

__global__ __launch_bounds__(256) void k_combos2(const float* __restrict__ h1, const float* __restrict__ bn1,
                                                 const float* __restrict__ ge1, const float* __restrict__ bte1,
                                                 const float* __restrict__ We2, const float* __restrict__ be2,
                                                 float* __restrict__ embE, float* __restrict__ embS) {
    __shared__ float v[D];
    int c = blockIdx.x, t = threadIdx.x;
    if (t < D) {
        float cnt = (float)(EE + NN);
        float m = bn1[t] / cnt;
        float var = bn1[D + t] / cnt - m * m;
        float r = rsqrtf(var + 1e-5f);
        float u = (h1[c*D + t] - m) * r * ge1[t] + bte1[t];
        v[t] = fmaxf(u, 0.f);
    }
    __syncthreads();
    if (t < D) {
        float acc = be2[t];
        for (int k = 0; k < D; k++) acc += v[k] * We2[k*D + t];
        if (c < NC) embE[c*D + t] = acc; else embS[(c-NC)*D + t] = acc;
    }
}

__global__ __launch_bounds__(256) void k_combos3(const float* __restrict__ embE, const float* __restrict__ sumsxf,
                                                 const int* __restrict__ tcnt, const float* __restrict__ Wa1,
                                                 const float* __restrict__ ba1, const int* __restrict__ hist,
                                                 float* __restrict__ h2, float* bn2) {
    __shared__ float a[2*D];
    int c = blockIdx.x, t = threadIdx.x;
    int etp = c >> 4;
    if (t < D) {
        a[t] = embE[c*D + t];
        float cn = fmaxf((float)tcnt[etp], 1.f);
        a[D + t] = sumsxf[etp*D + t] / cn;
    }
    __syncthreads();
    if (t < D) {
        float acc = ba1[t];
        for (int k = 0; k < 2*D; k++) acc += a[k] * Wa1[k*D + t];
        h2[c*D + t] = acc;
        float w = (float)hist[c];
        unsafeAtomicAdd(&bn2[t], w * acc);
        unsafeAtomicAdd(&bn2[D + t], w * acc * acc);
    }
}

// also writes RcT (200 x 608) for the coalesced attention score pass
__global__ __launch_bounds__(256) void k_combos4(const float* __restrict__ h2, const float* __restrict__ bn2,
                                                 const float* __restrict__ ga1, const float* __restrict__ bta1,
                                                 const float* __restrict__ Wa2, const float* __restrict__ ba2,
                                                 float* __restrict__ Rc, float* __restrict__ RcT) {
    __shared__ float v[D];
    int c = blockIdx.x, t = threadIdx.x;
    if (t < D) {
        float inv = 1.f / (float)EE;
        float m = bn2[t] * inv;
        float var = bn2[D + t] * inv - m * m;
        float r = rsqrtf(var + 1e-5f);
        float u = (h2[c*D + t] - m) * r * ga1[t] + bta1[t];
        v[t] = fmaxf(u, 0.f);
    }
    __syncthreads();
    if (t < D) {
        float acc = ba2[t];
        for (int k = 0; k < D; k++) acc += v[k] * Wa2[k*D + t];
        Rc[c*D + t] = acc;
        RcT[(size_t)t * NC + c] = acc;
    }
}

// ---------------- per-graph attention: qs precomputed by MFMA, 8-wave latency-hiding ----------------
__global__ __launch_bounds__(512) void k_attn(const float* __restrict__ qs,
                                              const float* __restrict__ Rc, const float* __restrict__ RcT,
                                              const int* __restrict__ hcnt, float* __restrict__ upd) {
    __shared__ float q[D];
    __shared__ float w[NC];
    __shared__ float red[16];
    __shared__ float part[8][D];
    int b = blockIdx.x, t = threadIdx.x;
    int wave = t >> 6, lane = t & 63;
    if (t < D) q[t] = qs[b*D + t];   // already scaled by 1/sqrt(200)
    __syncthreads();
    {
        float s0a = 0.f, s0b = 0.f, s0c = 0.f, s0d = 0.f;
        float s1a = 0.f, s1b = 0.f, s1c = 0.f, s1d = 0.f;
        for (int k = 0; k < D; k += 4) {
            float q0 = q[k], q1 = q[k+1], q2 = q[k+2], q3 = q[k+3];
            const float* r = RcT + (size_t)k * NC;
            s0a += q0 * r[t];
            s0b += q1 * r[NC + t];
            s0c += q2 * r[2*NC + t];
            s0d += q3 * r[3*NC + t];
            if (t < NC - 512) {
                s1a += q0 * r[t + 512];
                s1b += q1 * r[NC + t + 512];
                s1c += q2 * r[2*NC + t + 512];
                s1d += q3 * r[3*NC + t + 512];
            }
        }
        w[t] = (s0a + s0b) + (s0c + s0d);
        if (t < NC - 512) w[t + 512] = (s1a + s1b) + (s1c + s1d);
    }
    __syncthreads();
    float mx = -1e30f;
    for (int c = t; c < NC; c += 512) mx = fmaxf(mx, w[c]);
    for (int o = 32; o; o >>= 1) mx = fmaxf(mx, __shfl_xor(mx, o));
    if (lane == 0) red[wave] = mx;
    __syncthreads();
    mx = red[0];
    #pragma unroll
    for (int i = 1; i < 8; i++) mx = fmaxf(mx, red[i]);
    float sm = 0.f;
    for (int c = t; c < NC; c += 512) {
        float wv = (float)hcnt[b * NC + c] * __expf(w[c] - mx);
        w[c] = wv;
        sm += wv;
    }
    for (int o = 32; o; o >>= 1) sm += __shfl_xor(sm, o);
    if (lane == 0) red[8 + wave] = sm;
    __syncthreads();
    float tot = red[8];
    #pragma unroll
    for (int i = 1; i < 8; i++) tot += red[8 + i];
    float inv = 1.f / tot;
    float a4[4] = {0.f, 0.f, 0.f, 0.f};
    for (int c = wave * (NC/8); c < (wave + 1) * (NC/8); c++) {
        float wv = w[c];
        const float* r = Rc + c * D;
        #pragma unroll
        for (int j = 0; j < 4; j++) { int dd = lane + 64*j; if (dd < D) a4[j] += wv * r[dd]; }
    }
    #pragma unroll
    for (int j = 0; j < 4; j++) { int dd = lane + 64*j; if (dd < D) part[wave][dd] = a4[j]; }
    __syncthreads();
    if (t < D) {
        float s = part[0][t];
        #pragma unroll
        for (int i = 1; i < 8; i++) s += part[i][t];
        upd[b*D + t] = s * inv;
    }
}

// ---------------- weight packing: ks-major slices, B-fragment order, bf16 hi/lo ----------------
// blk = mat*91 + ks*13 + nt; each (mat,ks) slice = 26624 B contiguous.
// mats: 0=Wk[:D] 1=Wm[:D] 2=Wq 3=Wo1 4=Wo2 5=Watt 6=Wk[D:] 7=Wm[D:]
__global__ __launch_bounds__(256) void k_packW(const float* __restrict__ Wk, const float* __restrict__ Wm,
                                               const float* __restrict__ Wq, const float* __restrict__ Wo1,
                                               const float* __restrict__ Wo2, const float* __restrict__ Watt,
                                               short* __restrict__ Bpk) {
    int blk = blockIdx.x;
    int mat = blk / (NTILES * KSTEPS);
    int rem = blk - mat * (NTILES * KSTEPS);
    int ks = rem / NTILES, nt = rem - ks * NTILES;
    const float* W = (mat == 0) ? Wk : (mat == 1) ? Wm : (mat == 2) ? Wq : (mat == 3) ? Wo1 :
                     (mat == 4) ? Wo2 : (mat == 5) ? Watt : (mat == 6) ? (Wk + D*D) : (Wm + D*D);
    int t = threadIdx.x;
    for (int idx = t; idx < 1024; idx += 256) {
        int split = idx >> 9;
        int lane = (idx & 511) >> 3;
        int j = idx & 7;
        int n = nt * 16 + (lane & 15);
        int k = ks * 32 + ((lane >> 4) << 3) + j;
        float v = (k < D && n < D) ? W[k * D + n] : 0.f;
        short h = bf_hi(v);
        short out = split ? bf_hi(v - bf_f(h)) : h;
        Bpk[(size_t)blk * 1024 + idx] = out;
    }
}

// ---------------- MFMA GEMM core (512 threads, 128 rows, A-frags hoisted) ----------------
__device__ __forceinline__ void stage_load8(const short* __restrict__ g, int w, int lane, f32x4 rg[4]) {
    #pragma unroll
    for (int i = 0; i < 4; i++) {
        int c = w + 8 * i;
        if (c < NCHUNK) rg[i] = *(const f32x4*)((const char*)g + c * 1024 + lane * 16);
    }
}
__device__ __forceinline__ void stage_write8(short* l, int w, int lane, const f32x4 rg[4]) {
    #pragma unroll
    for (int i = 0; i < 4; i++) {
        int c = w + 8 * i;
        if (c < NCHUNK) *(f32x4*)((char*)l + c * 1024 + lane * 16) = rg[i];
    }
}

__device__ __forceinline__ void load_afrag(const float* __restrict__ A, int row, int quad, int ks,
                                           int preop, const float* __restrict__ bnacc, float invCnt,
                                           const float* __restrict__ g, const float* __restrict__ bb,
                                           bf16x8& ah, bf16x8& al) {
    int k0 = ks * 32 + quad * 8;
    float v[8];
    if (k0 < D) {   // k0 multiple of 8 < 200 => k0+8 <= 200, always in-row
        const float* src = A + (size_t)row * D + k0;
        float4 p0 = *(const float4*)src;
        float4 p1 = *(const float4*)(src + 4);
        v[0]=p0.x; v[1]=p0.y; v[2]=p0.z; v[3]=p0.w;
        v[4]=p1.x; v[5]=p1.y; v[6]=p1.z; v[7]=p1.w;
        if (preop) {
            float4 m0 = *(const float4*)(bnacc + k0);
            float4 m1 = *(const float4*)(bnacc + k0 + 4);
            float4 q0 = *(const float4*)(bnacc + D + k0);
            float4 q1 = *(const float4*)(bnacc + D + k0 + 4);
            float4 g0 = *(const float4*)(g + k0);
            float4 g1 = *(const float4*)(g + k0 + 4);
            float4 b0 = *(const float4*)(bb + k0);
            float4 b1 = *(const float4*)(bb + k0 + 4);
            float mm[8] = {m0.x,m0.y,m0.z,m0.w,m1.x,m1.y,m1.z,m1.w};
            float qq[8] = {q0.x,q0.y,q0.z,q0.w,q1.x,q1.y,q1.z,q1.w};
            float gg[8] = {g0.x,g0.y,g0.z,g0.w,g1.x,g1.y,g1.z,g1.w};
            float bv[8] = {b0.x,b0.y,b0.z,b0.w,b1.x,b1.y,b1.z,b1.w};
            #pragma unroll
            for (int j = 0; j < 8; j++) {
                float mj = mm[j] * invCnt;
                float var = qq[j] * invCnt - mj * mj;
                float rs = rsqrtf(var + 1e-5f);
                float s = rs * gg[j];
                v[j] = fmaxf(v[j] * s + (bv[j] - mj * s), 0.f);
            }
        }
    } else {
        #pragma unroll
        for (int j = 0; j < 8; j++) v[j] = 0.f;
    }
    #pragma unroll
    for (int j = 0; j < 8; j++) {
        short h = bf_hi(v[j]);
        ah[j] = h;
        al[j] = bf_hi(v[j] - bf_f(h));
    }
}

__device__ __forceinline__ void store_C(f32x4 acc[NTILES], float* __restrict__ C, int n0, int w, int lane,
                                        const float* __restrict__ bias, float postscale) {
    int colb = lane & 15, quad = lane >> 4;
    #pragma unroll
    for (int nt = 0; nt < NTILES; nt++) {
        int col = nt * 16 + colb;
        if (col < D) {
            float bj = bias ? bias[col] : 0.f;
            #pragma unroll
            for (int r = 0; r < 4; r++) {
                int row = n0 + w * 16 + quad * 4 + r;
                C[(size_t)row * D + col] = (acc[nt][r] + bj) * postscale;
            }
        }
    }
}

// one K-step: prefetch slice u+1, MFMA slice u from LDS, write prefetched, barrier.
// AH/AL are NAMED per-ks registers (static indexing, no scratch).
#define MMF_KS(MATV, KS, AH, AL, NUTOT, BASE)                                   \
    {                                                                           \
        int u_ = (MATV) * KSTEPS + (KS);                                        \
        int cur_ = u_ & 1;                                                      \
        if (u_ + 1 < (NUTOT))                                                   \
            stage_load8((BASE) + (size_t)(u_ + 1) * SLICE_SHORTS, w, lane, rg); \
        const bf16x8* B8_ = (const bf16x8*)(Bls + cur_ * SLICE_SHORTS);         \
        _Pragma("unroll")                                                       \
        for (int nt = 0; nt < NTILES; nt++) {                                   \
            bf16x8 bh = B8_[nt * 128 + lane];                                   \
            bf16x8 bl = B8_[nt * 128 + 64 + lane];                              \
            acc[nt] = __builtin_amdgcn_mfma_f32_16x16x32_bf16(AL, bh, acc[nt], 0, 0, 0); \
            acc[nt] = __builtin_amdgcn_mfma_f32_16x16x32_bf16(AH, bl, acc[nt], 0, 0, 0); \
            acc[nt] = __builtin_amdgcn_mfma_f32_16x16x32_bf16(AH, bh, acc[nt], 0, 0, 0); \
        }                                                                       \
        if (u_ + 1 < (NUTOT)) {                                                 \
            stage_write8(Bls + (cur_ ^ 1) * SLICE_SHORTS, w, lane, rg);         \
            __syncthreads();                                                    \
        }                                                                       \
    }

// ---------------- fused x @ {Wk[:D], Wm[:D], Wq} ----------------
__global__ __launch_bounds__(512, 2) void k_mmf3(const float* __restrict__ A, const short* __restrict__ Bpk,
                                                 const float* __restrict__ bq,
                                                 float* __restrict__ XK, float* __restrict__ XM, float* __restrict__ XQ) {
    __shared__ __align__(16) short Bls[2 * SLICE_SHORTS];   // 53248 B
    int t = threadIdx.x, w = t >> 6, lane = t & 63;
    int n0 = blockIdx.x * MROWS;
    int row = n0 + w * 16 + (lane & 15);
    int quad = lane >> 4;
    // A fragments loaded + converted ONCE, reused for all 3 mats
    bf16x8 ah0, al0, ah1, al1, ah2, al2, ah3, al3, ah4, al4, ah5, al5, ah6, al6;
    load_afrag(A, row, quad, 0, 0, nullptr, 0.f, nullptr, nullptr, ah0, al0);
    load_afrag(A, row, quad, 1, 0, nullptr, 0.f, nullptr, nullptr, ah1, al1);
    load_afrag(A, row, quad, 2, 0, nullptr, 0.f, nullptr, nullptr, ah2, al2);
    load_afrag(A, row, quad, 3, 0, nullptr, 0.f, nullptr, nullptr, ah3, al3);
    load_afrag(A, row, quad, 4, 0, nullptr, 0.f, nullptr, nullptr, ah4, al4);
    load_afrag(A, row, quad, 5, 0, nullptr, 0.f, nullptr, nullptr, ah5, al5);
    load_afrag(A, row, quad, 6, 0, nullptr, 0.f, nullptr, nullptr, ah6, al6);
    f32x4 rg[4];
    stage_load8(Bpk, w, lane, rg);
    stage_write8(Bls, w, lane, rg);
    __syncthreads();
    f32x4 acc[NTILES];
    for (int mat = 0; mat < 3; ++mat) {
        #pragma unroll
        for (int nt = 0; nt < NTILES; nt++) { acc[nt][0]=0.f; acc[nt][1]=0.f; acc[nt][2]=0.f; acc[nt][3]=0.f; }
        MMF_KS(mat, 0, ah0, al0, 3*KSTEPS, Bpk)
        MMF_KS(mat, 1, ah1, al1, 3*KSTEPS, Bpk)
        MMF_KS(mat, 2, ah2, al2, 3*KSTEPS, Bpk)
        MMF_KS(mat, 3, ah3, al3, 3*KSTEPS, Bpk)
        MMF_KS(mat, 4, ah4, al4, 3*KSTEPS, Bpk)
        MMF_KS(mat, 5, ah5, al5, 3*KSTEPS, Bpk)
        MMF_KS(mat, 6, ah6, al6, 3*KSTEPS, Bpk)
        if (mat == 0)      store_C(acc, XK, n0, w, lane, nullptr, 1.f);
        else if (mat == 1) store_C(acc, XM, n0, w, lane, nullptr, 1.f);
        else               store_C(acc, XQ, n0, w, lane, bq, 0.14142135623730950488f);
    }
}

// ---------------- generic MFMA matmul (one B), optional BN+relu preop ----------------
__global__ __launch_bounds__(512, 2) void k_mmf(const float* __restrict__ A, const short* __restrict__ Bmat,
                                                const float* __restrict__ bias, float* __restrict__ C,
                                                int preop, const float* __restrict__ bnacc, float invCnt,
                                                const float* __restrict__ g, const float* __restrict__ bb,
                                                float postscale) {
    __shared__ __align__(16) short Bls[2 * SLICE_SHORTS];
    int t = threadIdx.x, w = t >> 6, lane = t & 63;
    int n0 = blockIdx.x * MROWS;
    int row = n0 + w * 16 + (lane & 15);
    int quad = lane >> 4;
    bf16x8 ah0, al0, ah1, al1, ah2, al2, ah3, al3, ah4, al4, ah5, al5, ah6, al6;
    load_afrag(A, row, quad, 0, preop, bnacc, invCnt, g, bb, ah0, al0);
    load_afrag(A, row, quad, 1, preop, bnacc, invCnt, g, bb, ah1, al1);
    load_afrag(A, row, quad, 2, preop, bnacc, invCnt, g, bb, ah2, al2);
    load_afrag(A, row, quad, 3, preop, bnacc, invCnt, g, bb, ah3, al3);
    load_afrag(A, row, quad, 4, preop, bnacc, invCnt, g, bb, ah4, al4);
    load_afrag(A, row, quad, 5, preop, bnacc, invCnt, g, bb, ah5, al5);
    load_afrag(A, row, quad, 6, preop, bnacc, invCnt, g, bb, ah6, al6);
    f32x4 rg[4];
    stage_load8(Bmat, w, lane, rg);
    stage_write8(Bls, w, lane, rg);
    __syncthreads();
    f32x4 acc[NTILES];
    #pragma unroll
    for (int nt = 0; nt < NTILES; nt++) { acc[nt][0]=0.f; acc[nt][1]=0.f; acc[nt][2]=0.f; acc[nt][3]=0.f; }
    MMF_KS(0, 0, ah0, al0, KSTEPS, Bmat)
    MMF_KS(0, 1, ah1, al1, KSTEPS, Bmat)
    MMF_KS(0, 2, ah2, al2, KSTEPS, Bmat)
    MMF_KS(0, 3, ah3, al3, KSTEPS, Bmat)
    MMF_KS(0, 4, ah4, al4, KSTEPS, Bmat)
    MMF_KS(0, 5, ah5, al5, KSTEPS, Bmat)
    MMF_KS(0, 6, ah6, al6, KSTEPS, Bmat)
    store_C(acc, C, n0, w, lane, bias, postscale);
}

// 7-shuffle reduce-scatter: input 4 head partials/lane; output: lane group g (lane>>4) holds head-g total
__device__ __forceinline__ float head_reduce(float h0, float h1, float h2, float h3, int lane) {
    float ax = (lane < 32) ? h2 : h0;
    float ay = (lane < 32) ? h3 : h1;
    float u0 = ((lane < 32) ? h0 : h2) + __shfl_xor(ax, 32);
    float u1 = ((lane < 32) ? h1 : h3) + __shfl_xor(ay, 32);
    float bx = ((lane & 16) == 0) ? u1 : u0;
    float v  = (((lane & 16) == 0) ? u0 : u1) + __shfl_xor(bx, 16);
    v += __shfl_xor(v, 8);
    v += __shfl_xor(v, 4);
    v += __shfl_xor(v, 2);
    v += __shfl_xor(v, 1);
    return v;
}

// ---------------- edge softmax, src-CSR, wave per node; d = head*50 + lane ----------------
// Edge loop 2-way unrolled: two independent XK/GK row-gathers in flight per iteration
// (runtime-trip-count loops get ~1-deep pipelining from hipcc; manual MLP doubles it).
__global__ __launch_bounds__(256) void k_soft(const int* __restrict__ ei, const int* __restrict__ nt,
                                              const int* __restrict__ soff, const int* __restrict__ slist,
                                              const int* __restrict__ outdeg,
                                              const float* __restrict__ XQ, const float* __restrict__ XK,
                                              const float* __restrict__ GK, const float* __restrict__ SK,
                                              float* __restrict__ sc, float* __restrict__ scale) {
    int wave = threadIdx.x >> 6, lane = threadIdx.x & 63;
    int n = blockIdx.x * 4 + wave;
    if (n >= NN) return;
    bool act = lane < DH;
    int grp = lane >> 4;
    float qv0 = 0.f, qv1 = 0.f, qv2 = 0.f, qv3 = 0.f;
    if (act) {
        const float* q = XQ + (size_t)n * D + lane;
        qv0 = q[0]; qv1 = q[DH]; qv2 = q[2*DH]; qv3 = q[3*DH];
    }
    float den = 0.f;
    {   // self edge
        int tn = nt[n];
        float h0 = 0.f, h1 = 0.f, h2 = 0.f, h3 = 0.f;
        if (act) {
            const float* xk = XK + (size_t)n * D + lane;
            const float* sk = SK + (size_t)tn * D + lane;
            h0 = qv0 * (xk[0]    + sk[0]);
            h1 = qv1 * (xk[DH]   + sk[DH]);
            h2 = qv2 * (xk[2*DH] + sk[2*DH]);
            h3 = qv3 * (xk[3*DH] + sk[3*DH]);
        }
        float v = head_reduce(h0, h1, h2, h3, lane);
        float e = __expf(v);
        den += e;
        if ((lane & 15) == 0) sc[(size_t)(EE + n) * 4 + grp] = e;
    }
    int beg = soff[n], end = soff[n + 1];
    int i = beg;
    for (; i + 1 < end; i += 2) {
        int eA = slist[i], eB = slist[i + 1];
        int tailA = ei[EE + eA], tailB = ei[EE + eB];
        int gA = eA >> 10, gB = eB >> 10;
        float h0a = 0.f, h1a = 0.f, h2a = 0.f, h3a = 0.f;
        float h0b = 0.f, h1b = 0.f, h2b = 0.f, h3b = 0.f;
        if (act) {
            const float* xka = XK + (size_t)tailA * D + lane;
            const float* gka = GK + (size_t)gA * D + lane;
            const float* xkb = XK + (size_t)tailB * D + lane;
            const float* gkb = GK + (size_t)gB * D + lane;
            h0a = qv0 * (xka[0]    + gka[0]);
            h1a = qv1 * (xka[DH]   + gka[DH]);
            h2a = qv2 * (xka[2*DH] + gka[2*DH]);
            h3a = qv3 * (xka[3*DH] + gka[3*DH]);
            h0b = qv0 * (xkb[0]    + gkb[0]);
            h1b = qv1 * (xkb[DH]   + gkb[DH]);
            h2b = qv2 * (xkb[2*DH] + gkb[2*DH]);
            h3b = qv3 * (xkb[3*DH] + gkb[3*DH]);
        }
        float va = head_reduce(h0a, h1a, h2a, h3a, lane);
        float vb = head_reduce(h0b, h1b, h2b, h3b, lane);
        float exA = __expf(va), exB = __expf(vb);
        den += exA + exB;
        if ((lane & 15) == 0) {
            sc[(size_t)eA * 4 + grp] = exA;
            sc[(size_t)eB * 4 + grp] = exB;
        }
    }
    for (; i < end; i++) {
        int e_ = slist[i];
        int tail = ei[EE + e_];
        int g = e_ >> 10;
        float h0 = 0.f, h1 = 0.f, h2 = 0.f, h3 = 0.f;
        if (act) {
            const float* xk = XK + (size_t)tail * D + lane;
            const float* gk = GK + (size_t)g * D + lane;
            h0 = qv0 * (xk[0]    + gk[0]);
            h1 = qv1 * (xk[DH]   + gk[DH]);
            h2 = qv2 * (xk[2*DH] + gk[2*DH]);
            h3 = qv3 * (xk[3*DH] + gk[3*DH]);
        }
        float v = head_reduce(h0, h1, h2, h3, lane);
        float e = __expf(v);
        den += e;
        if ((lane & 15) == 0) sc[(size_t)e_ * 4 + grp] = e;
    }
    float cnt = (float)(outdeg[n] + 1);
    if ((lane & 15) == 0) scale[(size_t)n * 4 + grp] = cnt / den;
}

// ---------------- aggregation, dst-CSR, wave per node; d = head*50 + lane ----------------
// Edge loop 2-way unrolled (same MLP rationale as k_soft).
__global__ __launch_bounds__(256) void k_aggr(const int* __restrict__ ei, const int* __restrict__ nt,
                                              const int* __restrict__ doff, const int* __restrict__ dlist,
                                              const float* __restrict__ sc, const float* __restrict__ scale,
                                              const float* __restrict__ XM, const float* __restrict__ GM,
                                              const float* __restrict__ SM, float* __restrict__ aggr) {
    int wave = threadIdx.x >> 6, lane = threadIdx.x & 63;
    int n = blockIdx.x * 4 + wave;
    if (n >= NN) return;
    bool act = lane < DH;
    float acc0 = 0.f, acc1 = 0.f, acc2 = 0.f, acc3 = 0.f;
    {   // self edge
        int tn = nt[n];
        float4 ss = *(const float4*)&sc[(size_t)(EE + n) * 4];
        float4 sl = *(const float4*)&scale[(size_t)n * 4];
        if (act) {
            const float* xm = XM + (size_t)n * D + lane;
            const float* sm = SM + (size_t)tn * D + lane;
            acc0 += ss.x * sl.x * (xm[0]    + sm[0]);
            acc1 += ss.y * sl.y * (xm[DH]   + sm[DH]);
            acc2 += ss.z * sl.z * (xm[2*DH] + sm[2*DH]);
            acc3 += ss.w * sl.w * (xm[3*DH] + sm[3*DH]);
        }
    }
    int beg = doff[n], end = doff[n + 1];
    int i = beg;
    for (; i + 1 < end; i += 2) {
        int eA = dlist[i], eB = dlist[i + 1];
        int sA = ei[eA], sB = ei[eB];
        int gA = eA >> 10, gB = eB >> 10;
        float4 ssA = *(const float4*)&sc[(size_t)eA * 4];
        float4 slA = *(const float4*)&scale[(size_t)sA * 4];
        float4 ssB = *(const float4*)&sc[(size_t)eB * 4];
        float4 slB = *(const float4*)&scale[(size_t)sB * 4];
        if (act) {
            const float* xmA = XM + (size_t)sA * D + lane;
            const float* gmA = GM + (size_t)gA * D + lane;
            const float* xmB = XM + (size_t)sB * D + lane;
            const float* gmB = GM + (size_t)gB * D + lane;
            acc0 += ssA.x * slA.x * (xmA[0]    + gmA[0])    + ssB.x * slB.x * (xmB[0]    + gmB[0]);
            acc1 += ssA.y * slA.y * (xmA[DH]   + gmA[DH])   + ssB.y * slB.y * (xmB[DH]   + gmB[DH]);
            acc2 += ssA.z * slA.z * (xmA[2*DH] + gmA[2*DH]) + ssB.z * slB.z * (xmB[2*DH] + gmB[2*DH]);
            acc3 += ssA.w * slA.w * (xmA[3*DH] + gmA[3*DH]) + ssB.w * slB.w * (xmB[3*DH] + gmB[3*DH]);
        }
    }
    for (; i < end; i++) {
        int e = dlist[i];
        int s = ei[e];
        int g = e >> 10;
        float4 ss = *(const float4*)&sc[(size_t)e * 4];
        float4 sl = *(const float4*)&scale[(size_t)s * 4];
        if (act) {
            const float* xm = XM + (size_t)s * D + lane;
            const float* gm = GM + (size_t)g * D + lane;
            acc0 += ss.x * sl.x * (xm[0]    + gm[0]);
            acc1 += ss.y * sl.y * (xm[DH]   + gm[DH]);
            acc2 += ss.z * sl.z * (xm[2*DH] + gm[2*DH]);
            acc3 += ss.w * sl.w * (xm[3*DH] + gm[3*DH]);
        }
    }
    if (act) {
        float* out = aggr + (size_t)n * D + lane;
        out[0]    = acc0;
        out[DH]   = acc1;
        out[2*DH] = acc2;
        out[3*DH] = acc3;
    }
}

// ---------------- column stats for final BN ----------------
__global__ __launch_bounds__(256) void k_colstats(const float* __restrict__ T1, float* bn3) {
    int t = threadIdx.x;
    if (t >= D) return;
    int r0 = blockIdx.x * 256;
    float s = 0.f, q = 0.f;
    for (int r = r0; r < r0 + 256; r++) {
        float v = T1[(size_t)r * D + t];
        s += v; q += v * v;
    }
    unsafeAtomicAdd(&bn3[t], s);
    unsafeAtomicAdd(&bn3[D + t], q);
}

extern "C" void kernel_launch(void* const* d_in, const int* in_sizes, int n_in,
                              void* d_out, int out_size, void* d_ws, size_t ws_size,
                              hipStream_t stream) {
    const float* x    = (const float*)d_in[0];
    const float* sent = (const float*)d_in[2];
    const float* We1  = (const float*)d_in[3];
    const float* be1  = (const float*)d_in[4];
    const float* ge1  = (const float*)d_in[5];
    const float* bte1 = (const float*)d_in[6];
    const float* We2  = (const float*)d_in[7];
    const float* be2  = (const float*)d_in[8];
    const float* Wa1  = (const float*)d_in[9];
    const float* ba1  = (const float*)d_in[10];
    const float* ga1  = (const float*)d_in[11];
    const float* bta1 = (const float*)d_in[12];
    const float* Wa2  = (const float*)d_in[13];
    const float* ba2  = (const float*)d_in[14];
    const float* Watt = (const float*)d_in[15];
    const float* Wk   = (const float*)d_in[16];
    const float* bk   = (const float*)d_in[17];
    const float* Wm   = (const float*)d_in[18];
    const float* bm   = (const float*)d_in[19];
    const float* Wq   = (const float*)d_in[20];
    const float* bq   = (const float*)d_in[21];
    const float* Wo1  = (const float*)d_in[22];
    const float* bo1  = (const float*)d_in[23];
    const float* go1  = (const float*)d_in[24];
    const float* bto1 = (const float*)d_in[25];
    const float* Wo2  = (const float*)d_in[26];
    const float* bo2  = (const float*)d_in[27];
    const int* ei = (const int*)d_in[28];
    const int* et = (const int*)d_in[29];
    const int* nt = (const int*)d_in[30];

    char* ws = (char*)d_ws;
    size_t off = 0;
    auto alloc = [&](size_t bytes) -> char* {
        char* p = ws + off;
        off = (off + bytes + 255) & ~(size_t)255;
        return p;
    };
    // ---- zeroed region ----
    int*   hist   = (int*)  alloc(NC * 4);
    int*   ntcnt  = (int*)  alloc(NTY * 4);
    float* bn1    = (float*)alloc(2 * D * 4);
    float* bn2    = (float*)alloc(2 * D * 4);
    float* bn3    = (float*)alloc(2 * D * 4);
    float* sumsxf = (float*)alloc(NE * D * 4);
    int*   outdeg = (int*)  alloc(NN * 4);
    int*   indeg  = (int*)  alloc(NN * 4);
    int*   hcnt   = (int*)  alloc((size_t)BG * NC * 4);   // per-graph combo histogram
    float* updS   = (float*)alloc((size_t)384 * D * 4);   // rows: 0..255 upd, 256..259 embS, 260..383 pad
    size_t zero_end = off;
    // ---- rest ----
    int* tcnt = (int*)alloc(NE * 4);
    int* soff_ = (int*)alloc((NN + 1) * 4);
    int* doff_ = (int*)alloc((NN + 1) * 4);
    int* scur = (int*)alloc(NN * 4);
    int* dcur = (int*)alloc(NN * 4);
    int* bsA  = (int*)alloc(NB * 4);
    int* bsB  = (int*)alloc(NB * 4);
    int* slist = (int*)alloc((size_t)EE * 4);
    int* dlist = (int*)alloc((size_t)EE * 4);
    short* Bpk  = (short*)alloc((size_t)NMATS * NTILES * KSTEPS * 1024 * 2);   // 8 mats packed
    float* h1v   = (float*)alloc((size_t)NCT * D * 4);
    float* embE  = (float*)alloc((size_t)NC * D * 4);
    float* h2pre = (float*)alloc((size_t)NC * D * 4);
    float* Rc    = (float*)alloc((size_t)NC * D * 4);
    float* RcT   = (float*)alloc((size_t)D * NC * 4);
    float* qs    = (float*)alloc((size_t)BG * D * 4);
    float* GK    = (float*)alloc((size_t)384 * D * 4);    // rows 256..259 = SK
    float* GM    = (float*)alloc((size_t)384 * D * 4);    // rows 256..259 = SM
    float* sc    = (float*)alloc((size_t)EA * H * 4);
    float* XK    = (float*)alloc((size_t)NN * D * 4);
    float* XM    = (float*)alloc((size_t)NN * D * 4);
    float* XQ    = (float*)alloc((size_t)NN * D * 4);
    // aliases (liveness-checked):
    float* coef  = XK;            // dead before k_mmf3 writes XK
    float* scale = h1v;           // h1v dead before k_soft writes scale
    float* aggr  = XQ;            // XQ dead after k_soft
    float* T1    = XK;            // XK dead after k_soft
    float* embS  = updS + 256 * D;
    float* SK    = GK + 256 * D;
    float* SM    = GM + 256 * D;

    const int matstride = NTILES * KSTEPS * 1024;   // shorts per packed mat

    hipMemsetAsync(ws, 0, zero_end, stream);
    hipMemsetAsync(coef, 0, (size_t)NN * NE * 4, stream);

    k_packW  <<<NMATS * NTILES * KSTEPS, 256, 0, stream>>>(Wk, Wm, Wq, Wo1, Wo2, Watt, Bpk);
    k_hist   <<<BG, 256, 0, stream>>>(ei, et, nt, outdeg, indeg, hcnt, coef);
    k_hist2  <<<3, 256, 0, stream>>>(hcnt, hist);
    k_ntcnt  <<<NN / 256, 256, 0, stream>>>(nt, ntcnt);
    k_tcnt   <<<1, 64, 0, stream>>>(hist, tcnt);
    k_scan_a <<<NB, 256, 0, stream>>>(outdeg, indeg, bsA, bsB);
    k_scan_b <<<1, 256, 0, stream>>>(bsA, bsB, soff_, doff_);
    k_scan_c <<<NB, 256, 0, stream>>>(outdeg, indeg, bsA, bsB, soff_, doff_, scur, dcur);
    k_scatter<<<EE / 256, 256, 0, stream>>>(ei, scur, dcur, slist, dlist);
    k_xfsum3 <<<256, 256, 0, stream>>>(x, coef, sumsxf);
    // qs = sent @ Watt * (1/sqrt(200))   [MFMA, 2 blocks]
    k_mmf    <<<BG / MROWS, 512, 0, stream>>>(sent, Bpk + (size_t)5 * matstride, nullptr, qs,
                                              0, nullptr, 0.f, nullptr, nullptr, 0.07071067811865475f);
    k_combos1<<<NCT, 256, 0, stream>>>(We1, be1, hist, ntcnt, h1v, bn1);
    k_combos2<<<NCT, 256, 0, stream>>>(h1v, bn1, ge1, bte1, We2, be2, embE, embS);
    k_combos3<<<NC, 256, 0, stream>>>(embE, sumsxf, tcnt, Wa1, ba1, hist, h2pre, bn2);
    k_combos4<<<NC, 256, 0, stream>>>(h2pre, bn2, ga1, bta1, Wa2, ba2, Rc, RcT);
    k_attn   <<<BG, 512, 0, stream>>>(qs, Rc, RcT, hcnt, updS);
    // GK/GM = [upd; embS; 0-pad] @ {Wk[D:], Wm[D:]} + bias   [MFMA, 3 blocks each]
    k_mmf    <<<3, 512, 0, stream>>>(updS, Bpk + (size_t)6 * matstride, bk, GK,
                                     0, nullptr, 0.f, nullptr, nullptr, 1.f);
    k_mmf    <<<3, 512, 0, stream>>>(updS, Bpk + (size_t)7 * matstride, bm, GM,
                                     0, nullptr, 0.f, nullptr, nullptr, 1.f);
    k_mmf3   <<<NN / MROWS, 512, 0, stream>>>(x, Bpk, bq, XK, XM, XQ);
    k_soft   <<<NN / 4, 256, 0, stream>>>(ei, nt, soff_, slist, outdeg, XQ, XK, GK, SK, sc, scale);
    k_aggr   <<<NN / 4, 256, 0, stream>>>(ei, nt, doff_, dlist, sc, scale, XM, GM, SM, aggr);
    k_mmf    <<<NN / MROWS, 512, 0, stream>>>(aggr, Bpk + (size_t)3 * matstride, bo1, T1,
                                              0, nullptr, 0.f, nullptr, nullptr, 1.f);
    k_colstats<<<NN / 256, 256, 0, stream>>>(T1, bn3);
    k_mmf    <<<NN / MROWS, 512, 0, stream>>>(T1, Bpk + (size_t)4 * matstride, bo2, (float*)d_out,
                                              1, bn3, 1.f / (float)NN, go1, bto1, 1.f);
}